// Round 2
// baseline (428.736 us; speedup 1.0000x reference)
//
#include <hip/hip_runtime.h>
#include <hip/hip_bf16.h>
#include <cstdint>
#include <cstddef>

// ---------------- types ----------------
typedef __attribute__((ext_vector_type(8))) short     bf16x8;
typedef __attribute__((ext_vector_type(4))) float     f32x4;
typedef __attribute__((ext_vector_type(4))) unsigned short u16x4;

using as1_void = __attribute__((address_space(1))) void;
using as3_void = __attribute__((address_space(3))) void;

#define MFMA16(a,b,c) __builtin_amdgcn_mfma_f32_16x16x32_bf16((a),(b),(c),0,0,0)

__device__ __forceinline__ unsigned short f2bf(float f) {
  union { float f; unsigned u; } v; v.f = f;
  unsigned r = v.u + 0x7fffu + ((v.u >> 16) & 1u);
  return (unsigned short)(r >> 16);
}

__device__ __forceinline__ void gload16(const void* g, void* l) {
  __builtin_amdgcn_global_load_lds((const as1_void*)g, (as3_void*)l, 16, 0, 0);
}

// ---------------- problem constants ----------------
// B=2, U1=U2=3072, IF=256, FD=256, M=4, D=64
// ws layout (byte offsets)
constexpr size_t oXq  = 0;                       // bf16 [2*3072*256]
constexpr size_t oXk  = oXq + 1572864ull * 2;    // bf16 [2*3072*256]
constexpr size_t oWq  = oXk + 1572864ull * 2;    // bf16 [256*256]
constexpr size_t oWv  = oWq + 65536ull   * 2;    // bf16 [1024*256]
constexpr size_t oWm  = oWv + 262144ull  * 2;    // bf16 [256*256]
constexpr size_t oWo  = oWm + 65536ull   * 2;    // bf16 [256*256]
constexpr size_t oQb  = oWo + 65536ull   * 2;    // bf16 [8][3072][64]  (q/8)
constexpr size_t oKb  = oQb + 1572864ull * 2;    // bf16 [8][3072][64]
constexpr size_t oVb  = oKb + 1572864ull * 2;    // bf16 [8][256][3072] (V^T)
constexpr size_t oFu  = oVb + 6291456ull * 2;    // f32  [8][3072][256] fused
constexpr size_t oOut = oFu + 6291456ull * 4;    // f32  [8][3072][256] outp
constexpr size_t oSc  = oOut + 6291456ull * 4;   // f32  [8][3072] mode scores

// ================= kernel 1: f32 -> bf16 conversion of inputs =================
__global__ __launch_bounds__(256) void cvt_kernel(
    const float* __restrict__ q, const float* __restrict__ k,
    const float* __restrict__ wq, const float* __restrict__ wv,
    const float* __restrict__ wm, const float* __restrict__ wo,
    unsigned short* __restrict__ ws) {
  int i4 = (blockIdx.x * 256 + threadIdx.x) * 4;
  const float* src; int local;
  if (i4 < 1572864)       { src = q;  local = i4; }
  else if (i4 < 3145728)  { src = k;  local = i4 - 1572864; }
  else if (i4 < 3211264)  { src = wq; local = i4 - 3145728; }
  else if (i4 < 3473408)  { src = wv; local = i4 - 3211264; }
  else if (i4 < 3538944)  { src = wm; local = i4 - 3473408; }
  else                    { src = wo; local = i4 - 3538944; }
  f32x4 v = *(const f32x4*)(src + local);
  u16x4 o;
  o.x = f2bf(v.x); o.y = f2bf(v.y); o.z = f2bf(v.z); o.w = f2bf(v.w);
  *(u16x4*)(ws + i4) = o;
}

// ================= kernel 2: projections q,k,v =================
__global__ __launch_bounds__(256) void proj_kernel(const float* __restrict__ bv,
                                                   char* __restrict__ wsb) {
  int lane = threadIdx.x & 63, wid = threadIdx.x >> 6;
  int rowblk = blockIdx.x % 384;
  int ny = blockIdx.x / 384;
  int r0 = rowblk * 16;

  const unsigned short* X = (const unsigned short*)(wsb + (ny == 0 ? oXq : oXk));
  const unsigned short* W;
  if (ny <= 1) W = (const unsigned short*)(wsb + oWq);
  else         W = (const unsigned short*)(wsb + oWv) + (size_t)(ny - 2) * 256 * 256;

  int arow = r0 + (lane & 15);
  const unsigned short* Xp = X + (size_t)arow * 256 + ((lane >> 4) * 8);
  int n0 = wid * 64;

  f32x4 acc[4];
#pragma unroll
  for (int bt = 0; bt < 4; ++bt) acc[bt] = (f32x4){0.f, 0.f, 0.f, 0.f};

#pragma unroll
  for (int ks = 0; ks < 8; ++ks) {
    bf16x8 af = *(const bf16x8*)(Xp + ks * 32);
#pragma unroll
    for (int bt = 0; bt < 4; ++bt) {
      int n = n0 + bt * 16 + (lane & 15);
      bf16x8 bf = *(const bf16x8*)(W + (size_t)n * 256 + ks * 32 + ((lane >> 4) * 8));
      acc[bt] = MFMA16(af, bf, acc[bt]);
    }
  }

  int b = r0 / 3072, u0 = r0 % 3072;
  int ubase = u0 + ((lane >> 4) * 4);

  if (ny <= 1) {
    unsigned short* outp = (unsigned short*)(wsb + (ny == 0 ? oQb : oKb));
    float scale = (ny == 0) ? 0.125f : 1.0f;
    int m = wid;
#pragma unroll
    for (int bt = 0; bt < 4; ++bt) {
      int d = bt * 16 + (lane & 15);
#pragma unroll
      for (int r = 0; r < 4; ++r) {
        outp[((size_t)(b * 4 + m) * 3072 + (ubase + r)) * 64 + d] = f2bf(acc[bt][r] * scale);
      }
    }
  } else {
    unsigned short* vbT = (unsigned short*)(wsb + oVb);
    int mchunk = ny - 2;
#pragma unroll
    for (int bt = 0; bt < 4; ++bt) {
      int f = n0 + bt * 16 + (lane & 15);
      float bias = bv[mchunk * 256 + f];
      u16x4 pk;
#pragma unroll
      for (int r = 0; r < 4; ++r) pk[r] = f2bf(acc[bt][r] + bias);
      *(u16x4*)(vbT + ((size_t)(b * 4 + mchunk) * 256 + f) * 3072 + ubase) = pk;
    }
  }
}

// ================= kernel 3: flash attention (barrier-free, transposed) ======
// grid 768 x 128 threads (2 independent waves). bm = bid&7 pins (b,m) to an
// XCD so its K (384KB) + V^T (1.5MB) slice stays L2-resident.
// Each wave owns 16 q-rows (q = q0 + lane&15):
//   S^T = mfma(K, Q)    -> lane holds S[q][16 kv vals] -> lane-local softmax
//                          (+2 shfl_xor for the 4-lane-group combine)
//   P^T via 2KB wave-private LDS round-trip (XOR-chunk swizzle, no barrier)
//   O^T = mfma(V^T, P^T)-> (m,l) and rescale fully lane-local
// Zero __syncthreads. K frags for tile kt+1 prefetched into regs before PV.
__global__ __launch_bounds__(128) void attn_kernel(char* __restrict__ wsb) {
  __shared__ unsigned short sP[2][16 * 64];   // per-wave private P^T buffer

  const int lane = threadIdx.x & 63, wid = threadIdx.x >> 6;
  const int lq = lane & 15, hi = lane >> 4;
  const int bm = blockIdx.x & 7, qt = blockIdx.x >> 3;
  const int q0 = qt * 32 + wid * 16;

  const unsigned short* qb = (const unsigned short*)(wsb + oQb) + (size_t)bm * 3072 * 64;
  const unsigned short* kb = (const unsigned short*)(wsb + oKb) + (size_t)bm * 3072 * 64;
  const unsigned short* vb = (const unsigned short*)(wsb + oVb) + (size_t)bm * 256 * 3072;
  float* fused = (float*)(wsb + oFu) + (size_t)bm * 3072 * 256;

  // Q B-frag (persistent): B[d=hi*8+j][q=lq]
  const unsigned short* qp = qb + (size_t)(q0 + lq) * 64 + hi * 8;
  const bf16x8 qf0 = *(const bf16x8*)(qp);
  const bf16x8 qf1 = *(const bf16x8*)(qp + 32);

  f32x4 acc[16];
#pragma unroll
  for (int ft = 0; ft < 16; ++ft) acc[ft] = (f32x4){0.f, 0.f, 0.f, 0.f};
  float m = -1e30f, l = 0.f;

  char* myP = (char*)&sP[wid][0];
  const int key = lq & 7;

  // preload K frags for kt=0: A[kv=lq + 16t][d=hi*8+j]
  bf16x8 kc[4][2];
#pragma unroll
  for (int t = 0; t < 4; ++t) {
    const unsigned short* kp = kb + (size_t)(t * 16 + lq) * 64 + hi * 8;
    kc[t][0] = *(const bf16x8*)(kp);
    kc[t][1] = *(const bf16x8*)(kp + 32);
  }

  for (int kt = 0; kt < 48; ++kt) {
    const int kv0 = kt * 64;

    // ---- QK^T (swapped): s[t][r] = S[q=lq][kv0 + t*16 + hi*4 + r] ----
    f32x4 s[4];
#pragma unroll
    for (int t = 0; t < 4; ++t) {
      f32x4 z = (f32x4){0.f, 0.f, 0.f, 0.f};
      z = MFMA16(kc[t][0], qf0, z);
      z = MFMA16(kc[t][1], qf1, z);
      s[t] = z;
    }

    // ---- prefetch next K tile into regs (PV covers the latency) ----
    if (kt < 47) {
      const int kvn = kv0 + 64;
#pragma unroll
      for (int t = 0; t < 4; ++t) {
        const unsigned short* kp = kb + (size_t)(kvn + t * 16 + lq) * 64 + hi * 8;
        kc[t][0] = *(const bf16x8*)(kp);
        kc[t][1] = *(const bf16x8*)(kp + 32);
      }
    }

    // ---- lane-local online softmax ----
    float pmax = s[0][0];
#pragma unroll
    for (int t = 0; t < 4; ++t)
#pragma unroll
      for (int r = 0; r < 4; ++r) pmax = fmaxf(pmax, s[t][r]);
    pmax = fmaxf(pmax, __shfl_xor(pmax, 16));
    pmax = fmaxf(pmax, __shfl_xor(pmax, 32));

    if (__any(pmax > m + 8.0f)) {        // defer-max: rescale only on growth
      float mnew = fmaxf(m, pmax);
      float cr = __builtin_amdgcn_exp2f((m - mnew) * 1.44269504f);
#pragma unroll
      for (int ft = 0; ft < 16; ++ft) {
        acc[ft][0] *= cr; acc[ft][1] *= cr; acc[ft][2] *= cr; acc[ft][3] *= cr;
      }
      l *= cr; m = mnew;
    }

    const float mk = m * 1.44269504f;
    float ps[4][4];
    float psum = 0.f;
#pragma unroll
    for (int t = 0; t < 4; ++t)
#pragma unroll
      for (int r = 0; r < 4; ++r) {
        float p = __builtin_amdgcn_exp2f(s[t][r] * 1.44269504f - mk);
        ps[t][r] = p; psum += p;
      }
    psum += __shfl_xor(psum, 16);
    psum += __shfl_xor(psum, 32);
    l += psum;

    // ---- pack P^T -> wave-private LDS (XOR-chunk swizzle, 2-way free) ----
#pragma unroll
    for (int t = 0; t < 4; ++t) {
      unsigned w0 = (unsigned)f2bf(ps[t][0]) | ((unsigned)f2bf(ps[t][1]) << 16);
      unsigned w1 = (unsigned)f2bf(ps[t][2]) | ((unsigned)f2bf(ps[t][3]) << 16);
      int c = (2 * t + (hi >> 1)) ^ key;
      *(uint2*)(myP + lq * 128 + (c << 4) + ((hi & 1) << 3)) = make_uint2(w0, w1);
    }
    // read P^T B-frags: B[kv=t2*32+hi*8+j][q=lq]
    bf16x8 pb0 = *(const bf16x8*)(myP + lq * 128 + (((0 * 4 + hi) ^ key) << 4));
    bf16x8 pb1 = *(const bf16x8*)(myP + lq * 128 + (((1 * 4 + hi) ^ key) << 4));

    // ---- PV (swapped): acc[ft] += V^T-frag x P^T-frag ----
#pragma unroll
    for (int ft = 0; ft < 16; ++ft) {
      const unsigned short* vp = vb + (size_t)(ft * 16 + lq) * 3072 + kv0 + hi * 8;
      bf16x8 vf0 = *(const bf16x8*)(vp);
      bf16x8 vf1 = *(const bf16x8*)(vp + 32);
      acc[ft] = MFMA16(vf0, pb0, acc[ft]);
      acc[ft] = MFMA16(vf1, pb1, acc[ft]);
    }
  }

  // ---- epilogue: O = acc / l ; store O[q][f] (coalesced 64B groups) ----
  const float inv = 1.0f / l;
  float* orow = fused + (size_t)(q0 + lq) * 256 + hi * 4;
#pragma unroll
  for (int ft = 0; ft < 16; ++ft) {
    f32x4 o = acc[ft];
    o[0] *= inv; o[1] *= inv; o[2] *= inv; o[3] *= inv;
    *(f32x4*)(orow + ft * 16) = o;
  }
}

// ================= kernel 4: FFN + LN + agg scores =================
__global__ __launch_bounds__(256) void ffn_kernel(char* __restrict__ wsb,
                                                  const float* __restrict__ bmid,
                                                  const float* __restrict__ bout,
                                                  const float* __restrict__ lng,
                                                  const float* __restrict__ lnb,
                                                  const float* __restrict__ wagg,
                                                  const float* __restrict__ bagg) {
  __shared__ unsigned short sA[16 * 256];
  __shared__ unsigned short sM[16 * 256];
  __shared__ float redS[4][16], redQ[4][16], redC[4][16];

  int lane = threadIdx.x & 63, wid = threadIdx.x >> 6;
  int r0 = blockIdx.x * 16;

  const float* fused = (const float*)(wsb + oFu);
  float* outp = (float*)(wsb + oOut);
  float* scores = (float*)(wsb + oSc);
  const unsigned short* Wm = (const unsigned short*)(wsb + oWm);
  const unsigned short* Wo = (const unsigned short*)(wsb + oWo);

  {
    int t = threadIdx.x;
    const float* src = fused + (size_t)r0 * 256 + t * 16;
    int row = (t * 16) >> 8;
    int k0 = (t * 16) & 255;
    f32x4 v0 = *(const f32x4*)(src);
    f32x4 v1 = *(const f32x4*)(src + 4);
    f32x4 v2 = *(const f32x4*)(src + 8);
    f32x4 v3 = *(const f32x4*)(src + 12);
    int cA = k0 >> 3;
    unsigned short* pA = &sA[row * 256 + ((cA ^ (row & 7)) << 3)];
    unsigned short* pB = &sA[row * 256 + (((cA + 1) ^ (row & 7)) << 3)];
    pA[0] = f2bf(v0.x); pA[1] = f2bf(v0.y); pA[2] = f2bf(v0.z); pA[3] = f2bf(v0.w);
    pA[4] = f2bf(v1.x); pA[5] = f2bf(v1.y); pA[6] = f2bf(v1.z); pA[7] = f2bf(v1.w);
    pB[0] = f2bf(v2.x); pB[1] = f2bf(v2.y); pB[2] = f2bf(v2.z); pB[3] = f2bf(v2.w);
    pB[4] = f2bf(v3.x); pB[5] = f2bf(v3.y); pB[6] = f2bf(v3.z); pB[7] = f2bf(v3.w);
  }
  __syncthreads();

  int n0 = wid * 64;
  int rowb = (lane >> 4) * 4;

  f32x4 acc1[4];
#pragma unroll
  for (int bt = 0; bt < 4; ++bt) acc1[bt] = (f32x4){0.f, 0.f, 0.f, 0.f};
#pragma unroll
  for (int ks = 0; ks < 8; ++ks) {
    int row = lane & 15;
    bf16x8 af = *(const bf16x8*)&sA[row * 256 + (((ks * 4 + (lane >> 4)) ^ (row & 7)) << 3)];
#pragma unroll
    for (int bt = 0; bt < 4; ++bt) {
      int n = n0 + bt * 16 + (lane & 15);
      bf16x8 bf = *(const bf16x8*)(Wm + (size_t)n * 256 + ks * 32 + ((lane >> 4) * 8));
      acc1[bt] = MFMA16(af, bf, acc1[bt]);
    }
  }
#pragma unroll
  for (int bt = 0; bt < 4; ++bt) {
    int n = n0 + bt * 16 + (lane & 15);
    float bb = bmid[n];
#pragma unroll
    for (int r = 0; r < 4; ++r) {
      float x = acc1[bt][r] + bb;
      float g = 0.5f * x * (1.0f + erff(x * 0.7071067811865475f));
      int row = rowb + r;
      sM[row * 256 + (((n >> 3) ^ (row & 7)) << 3) + (n & 7)] = f2bf(g);
    }
  }
  __syncthreads();

  f32x4 acc2[4];
#pragma unroll
  for (int bt = 0; bt < 4; ++bt) acc2[bt] = (f32x4){0.f, 0.f, 0.f, 0.f};
#pragma unroll
  for (int ks = 0; ks < 8; ++ks) {
    int row = lane & 15;
    bf16x8 af = *(const bf16x8*)&sM[row * 256 + (((ks * 4 + (lane >> 4)) ^ (row & 7)) << 3)];
#pragma unroll
    for (int bt = 0; bt < 4; ++bt) {
      int n = n0 + bt * 16 + (lane & 15);
      bf16x8 bf = *(const bf16x8*)(Wo + (size_t)n * 256 + ks * 32 + ((lane >> 4) * 8));
      acc2[bt] = MFMA16(af, bf, acc2[bt]);
    }
  }

  float xv[4][4];
  float sS[4] = {0.f, 0.f, 0.f, 0.f}, sQ[4] = {0.f, 0.f, 0.f, 0.f};
#pragma unroll
  for (int bt = 0; bt < 4; ++bt) {
    int n = n0 + bt * 16 + (lane & 15);
    float bo = bout[n];
#pragma unroll
    for (int r = 0; r < 4; ++r) {
      float x = acc2[bt][r] + bo + fused[(size_t)(r0 + rowb + r) * 256 + n];
      xv[bt][r] = x;
      sS[r] += x;
      sQ[r] += x * x;
    }
  }
#pragma unroll
  for (int r = 0; r < 4; ++r) {
#pragma unroll
    for (int off = 1; off < 16; off <<= 1) {
      sS[r] += __shfl_xor(sS[r], off);
      sQ[r] += __shfl_xor(sQ[r], off);
    }
  }
  if ((lane & 15) == 0) {
#pragma unroll
    for (int r = 0; r < 4; ++r) { redS[wid][rowb + r] = sS[r]; redQ[wid][rowb + r] = sQ[r]; }
  }
  __syncthreads();

  float scp[4] = {0.f, 0.f, 0.f, 0.f};
#pragma unroll
  for (int r = 0; r < 4; ++r) {
    int row = rowb + r;
    float ts = redS[0][row] + redS[1][row] + redS[2][row] + redS[3][row];
    float tq = redQ[0][row] + redQ[1][row] + redQ[2][row] + redQ[3][row];
    float mean = ts * (1.0f / 256.0f);
    float var = tq * (1.0f / 256.0f) - mean * mean;
    float rs = rsqrtf(var + 1e-12f);
#pragma unroll
    for (int bt = 0; bt < 4; ++bt) {
      int n = n0 + bt * 16 + (lane & 15);
      float o = (xv[bt][r] - mean) * rs * lng[n] + lnb[n];
      outp[(size_t)(r0 + row) * 256 + n] = o;
      scp[r] += o * wagg[n];
    }
  }
#pragma unroll
  for (int r = 0; r < 4; ++r) {
#pragma unroll
    for (int off = 1; off < 16; off <<= 1) scp[r] += __shfl_xor(scp[r], off);
  }
  if ((lane & 15) == 0) {
#pragma unroll
    for (int r = 0; r < 4; ++r) redC[wid][rowb + r] = scp[r];
  }
  __syncthreads();
  if (wid == 0 && lane < 16) {
    scores[r0 + lane] = redC[0][lane] + redC[1][lane] + redC[2][lane] + redC[3][lane] + bagg[0];
  }
}

// ================= kernel 5: mode-softmax aggregation =================
__global__ __launch_bounds__(256) void agg_kernel(const char* __restrict__ wsb,
                                                  float* __restrict__ out) {
  int gid = blockIdx.x * 256 + threadIdx.x;
  int bu = gid >> 6;
  int f0 = (gid & 63) * 4;
  int b = bu / 3072, u = bu % 3072;
  const float* scores = (const float*)(wsb + oSc);
  const float* outp = (const float*)(wsb + oOut);

  float sc[4];
#pragma unroll
  for (int m = 0; m < 4; ++m) sc[m] = scores[(size_t)(b * 4 + m) * 3072 + u];
  float mx = fmaxf(fmaxf(sc[0], sc[1]), fmaxf(sc[2], sc[3]));
  float e[4]; float sum = 0.f;
#pragma unroll
  for (int m = 0; m < 4; ++m) { e[m] = __expf(sc[m] - mx); sum += e[m]; }
  float inv = 1.0f / sum;

  f32x4 o = (f32x4){0.f, 0.f, 0.f, 0.f};
#pragma unroll
  for (int m = 0; m < 4; ++m) {
    f32x4 v = *(const f32x4*)(outp + ((size_t)(b * 4 + m) * 3072 + u) * 256 + f0);
    float w = e[m] * inv;
    o.x += v.x * w; o.y += v.y * w; o.z += v.z * w; o.w += v.w * w;
  }
  *(f32x4*)(out + (size_t)bu * 256 + f0) = o;
}

// ================= launcher =================
extern "C" void kernel_launch(void* const* d_in, const int* in_sizes, int n_in,
                              void* d_out, int out_size, void* d_ws, size_t ws_size,
                              hipStream_t stream) {
  const float* q  = (const float*)d_in[0];
  const float* k  = (const float*)d_in[1];
  const float* wq = (const float*)d_in[2];
  const float* wv = (const float*)d_in[3];
  const float* bv = (const float*)d_in[4];
  const float* wm = (const float*)d_in[5];
  const float* bm = (const float*)d_in[6];
  const float* wo = (const float*)d_in[7];
  const float* bo = (const float*)d_in[8];
  const float* lg = (const float*)d_in[9];
  const float* lb = (const float*)d_in[10];
  const float* wa = (const float*)d_in[11];
  const float* ba = (const float*)d_in[12];
  char* wsb = (char*)d_ws;

  cvt_kernel<<<3520, 256, 0, stream>>>(q, k, wq, wv, wm, wo, (unsigned short*)wsb);
  proj_kernel<<<2304, 256, 0, stream>>>(bv, wsb);
  attn_kernel<<<768, 128, 0, stream>>>(wsb);
  ffn_kernel<<<1536, 256, 0, stream>>>(wsb, bm, bo, lg, lb, wa, ba);
  agg_kernel<<<1536, 256, 0, stream>>>(wsb, (float*)d_out);
}

// Round 3
// 358.327 us; speedup vs baseline: 1.1965x; 1.1965x over previous
//
#include <hip/hip_runtime.h>
#include <hip/hip_bf16.h>
#include <cstdint>
#include <cstddef>

// ---------------- types ----------------
typedef __attribute__((ext_vector_type(8))) short     bf16x8;
typedef __attribute__((ext_vector_type(4))) float     f32x4;
typedef __attribute__((ext_vector_type(4))) unsigned short u16x4;

using as1_void = __attribute__((address_space(1))) void;
using as3_void = __attribute__((address_space(3))) void;

#define MFMA16(a,b,c) __builtin_amdgcn_mfma_f32_16x16x32_bf16((a),(b),(c),0,0,0)

__device__ __forceinline__ unsigned short f2bf(float f) {
  union { float f; unsigned u; } v; v.f = f;
  unsigned r = v.u + 0x7fffu + ((v.u >> 16) & 1u);
  return (unsigned short)(r >> 16);
}
__device__ __forceinline__ float bf2f(unsigned short h) {
  union { unsigned u; float f; } v; v.u = ((unsigned)h) << 16; return v.f;
}

__device__ __forceinline__ void gload16(const void* g, void* l) {
  __builtin_amdgcn_global_load_lds((const as1_void*)g, (as3_void*)l, 16, 0, 0);
}

// ---------------- problem constants ----------------
// B=2, U1=U2=3072, IF=256, FD=256, M=4, D=64
constexpr size_t oXq  = 0;                       // bf16 [2*3072*256]
constexpr size_t oXk  = oXq + 1572864ull * 2;    // bf16 [2*3072*256]
constexpr size_t oWq  = oXk + 1572864ull * 2;    // bf16 [256*256]
constexpr size_t oWv  = oWq + 65536ull   * 2;    // bf16 [1024*256]
constexpr size_t oWm  = oWv + 262144ull  * 2;    // bf16 [256*256]
constexpr size_t oWo  = oWm + 65536ull   * 2;    // bf16 [256*256]
constexpr size_t oQb  = oWo + 65536ull   * 2;    // bf16 [8][3072][64]  (q/8)
constexpr size_t oKb  = oQb + 1572864ull * 2;    // bf16 [8][3072][64]
constexpr size_t oVb  = oKb + 1572864ull * 2;    // bf16 [8][256][3072] (V^T)
constexpr size_t oFu  = oVb + 6291456ull * 2;    // bf16 [8][3072][256] fused

// ================= kernel 1: f32 -> bf16 conversion of inputs =================
__global__ __launch_bounds__(256) void cvt_kernel(
    const float* __restrict__ q, const float* __restrict__ k,
    const float* __restrict__ wq, const float* __restrict__ wv,
    const float* __restrict__ wm, const float* __restrict__ wo,
    unsigned short* __restrict__ ws) {
  int i4 = (blockIdx.x * 256 + threadIdx.x) * 4;
  const float* src; int local;
  if (i4 < 1572864)       { src = q;  local = i4; }
  else if (i4 < 3145728)  { src = k;  local = i4 - 1572864; }
  else if (i4 < 3211264)  { src = wq; local = i4 - 3145728; }
  else if (i4 < 3473408)  { src = wv; local = i4 - 3211264; }
  else if (i4 < 3538944)  { src = wm; local = i4 - 3473408; }
  else                    { src = wo; local = i4 - 3538944; }
  f32x4 v = *(const f32x4*)(src + local);
  u16x4 o;
  o.x = f2bf(v.x); o.y = f2bf(v.y); o.z = f2bf(v.z); o.w = f2bf(v.w);
  *(u16x4*)(ws + i4) = o;
}

// ================= kernel 2: projections q,k,v =================
__global__ __launch_bounds__(256) void proj_kernel(const float* __restrict__ bv,
                                                   char* __restrict__ wsb) {
  int lane = threadIdx.x & 63, wid = threadIdx.x >> 6;
  int rowblk = blockIdx.x % 384;
  int ny = blockIdx.x / 384;
  int r0 = rowblk * 16;

  const unsigned short* X = (const unsigned short*)(wsb + (ny == 0 ? oXq : oXk));
  const unsigned short* W;
  if (ny <= 1) W = (const unsigned short*)(wsb + oWq);
  else         W = (const unsigned short*)(wsb + oWv) + (size_t)(ny - 2) * 256 * 256;

  int arow = r0 + (lane & 15);
  const unsigned short* Xp = X + (size_t)arow * 256 + ((lane >> 4) * 8);
  int n0 = wid * 64;

  f32x4 acc[4];
#pragma unroll
  for (int bt = 0; bt < 4; ++bt) acc[bt] = (f32x4){0.f, 0.f, 0.f, 0.f};

#pragma unroll
  for (int ks = 0; ks < 8; ++ks) {
    bf16x8 af = *(const bf16x8*)(Xp + ks * 32);
#pragma unroll
    for (int bt = 0; bt < 4; ++bt) {
      int n = n0 + bt * 16 + (lane & 15);
      bf16x8 bf = *(const bf16x8*)(W + (size_t)n * 256 + ks * 32 + ((lane >> 4) * 8));
      acc[bt] = MFMA16(af, bf, acc[bt]);
    }
  }

  int b = r0 / 3072, u0 = r0 % 3072;
  int ubase = u0 + ((lane >> 4) * 4);

  if (ny <= 1) {
    unsigned short* outp = (unsigned short*)(wsb + (ny == 0 ? oQb : oKb));
    float scale = (ny == 0) ? 0.125f : 1.0f;
    int m = wid;
#pragma unroll
    for (int bt = 0; bt < 4; ++bt) {
      int d = bt * 16 + (lane & 15);
#pragma unroll
      for (int r = 0; r < 4; ++r) {
        outp[((size_t)(b * 4 + m) * 3072 + (ubase + r)) * 64 + d] = f2bf(acc[bt][r] * scale);
      }
    }
  } else {
    unsigned short* vbT = (unsigned short*)(wsb + oVb);
    int mchunk = ny - 2;
#pragma unroll
    for (int bt = 0; bt < 4; ++bt) {
      int f = n0 + bt * 16 + (lane & 15);
      float bias = bv[mchunk * 256 + f];
      u16x4 pk;
#pragma unroll
      for (int r = 0; r < 4; ++r) pk[r] = f2bf(acc[bt][r] + bias);
      *(u16x4*)(vbT + ((size_t)(b * 4 + mchunk) * 256 + f) * 3072 + ubase) = pk;
    }
  }
}

// ================= kernel 3: flash attention =================
// grid 384 x 128 (2 waves). Block = 64 q-rows; each wave owns 32 (2 groups
// of 16). bm = bid&7 pins (b,m)'s K/V slice to one XCD L2.
// K,V staged in LDS via global_load_lds (pre-swizzled source, swizzled reads
// -> 0 bank conflicts, proven in R1). Lane-local online softmax (swapped
// QK^T), wave-private P buffer, 2 barriers/tile.
__global__ __launch_bounds__(128, 2) void attn_kernel(char* __restrict__ wsb) {
  __shared__ unsigned short sK[64 * 64];       // 8KB  [kv][d]  chunk-swizzled
  __shared__ unsigned short sV[256 * 64];      // 32KB [f][kv]  chunk-swizzled
  __shared__ unsigned short sP[4][16 * 64];    // 8KB  [wid*2+g] private P^T

  const int lane = threadIdx.x & 63, wid = threadIdx.x >> 6;
  const int lq = lane & 15, hi = lane >> 4;
  const int lr3 = lane >> 3, lc3 = lane & 7;
  const int bm = blockIdx.x & 7, qt = blockIdx.x >> 3;
  const int q0w = qt * 64 + wid * 32;
  const int key = lq & 7;

  const unsigned short* qb = (const unsigned short*)(wsb + oQb) + (size_t)bm * 3072 * 64;
  const unsigned short* kb = (const unsigned short*)(wsb + oKb) + (size_t)bm * 3072 * 64;
  const unsigned short* vb = (const unsigned short*)(wsb + oVb) + (size_t)bm * 256 * 3072;
  unsigned short* fuB = (unsigned short*)(wsb + oFu) + (size_t)bm * 3072 * 256;

  // persistent Q B-frags: B[d = hi*8+j][q = lq] per group
  bf16x8 qf[2][2];
#pragma unroll
  for (int g = 0; g < 2; ++g) {
    const unsigned short* qp = qb + (size_t)(q0w + g * 16 + lq) * 64 + hi * 8;
    qf[g][0] = *(const bf16x8*)(qp);
    qf[g][1] = *(const bf16x8*)(qp + 32);
  }

  f32x4 acc[2][16];
#pragma unroll
  for (int g = 0; g < 2; ++g)
#pragma unroll
    for (int ft = 0; ft < 16; ++ft) acc[g][ft] = (f32x4){0.f, 0.f, 0.f, 0.f};
  float mrun[2] = {-1e30f, -1e30f}, lrun[2] = {0.f, 0.f};

  char* myP0 = (char*)&sP[wid * 2][0];
  char* myP1 = (char*)&sP[wid * 2 + 1][0];

  for (int kt = 0; kt < 48; ++kt) {
    const int kv0 = kt * 64;

    // ---- stage K tile: 8 chunks of 1KB (this wave: 4) ----
#pragma unroll
    for (int i = 0; i < 4; ++i) {
      int ch = wid * 4 + i;
      int r = ch * 8 + lr3;
      int cs = lc3 ^ (r & 7);
      gload16(kb + (size_t)(kv0 + r) * 64 + cs * 8, &sK[ch * 512]);
    }
    // ---- stage V^T tile: 32 chunks (this wave: 16) ----
#pragma unroll
    for (int i = 0; i < 16; ++i) {
      int ch = i * 2 + wid;
      int f = ch * 8 + lr3;
      int cs = lc3 ^ (f & 7);
      gload16(vb + (size_t)f * 3072 + kv0 + cs * 8, &sV[ch * 512]);
    }
    __syncthreads();   // drains vmcnt -> tile staged

    // ---- K A-frags (shared across both q-groups) ----
    bf16x8 kc[4][2];
#pragma unroll
    for (int t = 0; t < 4; ++t) {
      int kvl = t * 16 + lq;
      const unsigned short* kr = &sK[kvl * 64];
      kc[t][0] = *(const bf16x8*)(kr + ((hi ^ key) * 8));
      kc[t][1] = *(const bf16x8*)(kr + (((hi + 4) ^ key) * 8));
    }

    // ---- QK^T both groups: s[g][t][r] = S[q][kv0 + t*16 + hi*4 + r] ----
    f32x4 s[2][4];
#pragma unroll
    for (int g = 0; g < 2; ++g)
#pragma unroll
      for (int t = 0; t < 4; ++t) {
        f32x4 z = (f32x4){0.f, 0.f, 0.f, 0.f};
        z = MFMA16(kc[t][0], qf[g][0], z);
        z = MFMA16(kc[t][1], qf[g][1], z);
        s[g][t] = z;
      }

    // ---- lane-local online softmax per group ----
    bf16x8 pb[2][2];
#pragma unroll
    for (int g = 0; g < 2; ++g) {
      float pmax = s[g][0][0];
#pragma unroll
      for (int t = 0; t < 4; ++t)
#pragma unroll
        for (int r = 0; r < 4; ++r) pmax = fmaxf(pmax, s[g][t][r]);
      pmax = fmaxf(pmax, __shfl_xor(pmax, 16));
      pmax = fmaxf(pmax, __shfl_xor(pmax, 32));

      if (__any(pmax > mrun[g] + 8.0f)) {   // defer-max rescale
        float mnew = fmaxf(mrun[g], pmax);
        float cr = __builtin_amdgcn_exp2f((mrun[g] - mnew) * 1.44269504f);
#pragma unroll
        for (int ft = 0; ft < 16; ++ft) {
          acc[g][ft][0] *= cr; acc[g][ft][1] *= cr;
          acc[g][ft][2] *= cr; acc[g][ft][3] *= cr;
        }
        lrun[g] *= cr; mrun[g] = mnew;
      }

      const float mk = mrun[g] * 1.44269504f;
      float psum = 0.f;
#pragma unroll
      for (int t = 0; t < 4; ++t)
#pragma unroll
        for (int r = 0; r < 4; ++r) {
          float p = __builtin_amdgcn_exp2f(s[g][t][r] * 1.44269504f - mk);
          s[g][t][r] = p; psum += p;
        }
      psum += __shfl_xor(psum, 16);
      psum += __shfl_xor(psum, 32);
      lrun[g] += psum;

      // pack P^T into wave-private LDS (swizzled, no barrier needed)
      char* myP = g ? myP1 : myP0;
#pragma unroll
      for (int t = 0; t < 4; ++t) {
        unsigned w0 = (unsigned)f2bf(s[g][t][0]) | ((unsigned)f2bf(s[g][t][1]) << 16);
        unsigned w1 = (unsigned)f2bf(s[g][t][2]) | ((unsigned)f2bf(s[g][t][3]) << 16);
        int c = (2 * t + (hi >> 1)) ^ key;
        *(uint2*)(myP + lq * 128 + (c << 4) + ((hi & 1) << 3)) = make_uint2(w0, w1);
      }
      pb[g][0] = *(const bf16x8*)(myP + lq * 128 + ((hi ^ key) << 4));
      pb[g][1] = *(const bf16x8*)(myP + lq * 128 + (((4 + hi) ^ key) << 4));
    }

    // ---- PV: acc[g][ft] += V^T-frag x P^T-frag ----
    __builtin_amdgcn_s_setprio(1);
#pragma unroll
    for (int ft = 0; ft < 16; ++ft) {
      const unsigned short* vr = &sV[(ft * 16 + lq) * 64];
      bf16x8 vf0 = *(const bf16x8*)(vr + ((hi ^ key) * 8));
      bf16x8 vf1 = *(const bf16x8*)(vr + (((4 + hi) ^ key) * 8));
      acc[0][ft] = MFMA16(vf0, pb[0][0], acc[0][ft]);
      acc[0][ft] = MFMA16(vf1, pb[0][1], acc[0][ft]);
      acc[1][ft] = MFMA16(vf0, pb[1][0], acc[1][ft]);
      acc[1][ft] = MFMA16(vf1, pb[1][1], acc[1][ft]);
    }
    __builtin_amdgcn_s_setprio(0);
    __syncthreads();   // all reads done before next stage
  }

  // ---- epilogue: O = acc/l, store bf16 fused[q][f] ----
#pragma unroll
  for (int g = 0; g < 2; ++g) {
    const float inv = 1.0f / lrun[g];
    unsigned short* orow = fuB + (size_t)(q0w + g * 16 + lq) * 256 + hi * 4;
#pragma unroll
    for (int ft = 0; ft < 16; ++ft) {
      u16x4 pk;
#pragma unroll
      for (int r = 0; r < 4; ++r) pk[r] = f2bf(acc[g][ft][r] * inv);
      *(u16x4*)(orow + ft * 16) = pk;
    }
  }
}

// ================= kernel 4: FFN + LN + mode-softmax aggregation =============
// grid 384 = 2 b x 192 u-blocks of 16. Block rows: row = m*16 + du (64 rows).
// GEMM1+gelu -> GEMM2+residual+LN -> agg scores -> in-register mode softmax
// and weighted sum -> d_out. No outp buffer, no separate agg kernel.
__global__ __launch_bounds__(256, 2) void ffn_kernel(char* __restrict__ wsb,
                                                     const float* __restrict__ bmid,
                                                     const float* __restrict__ bout,
                                                     const float* __restrict__ lng,
                                                     const float* __restrict__ lnb,
                                                     const float* __restrict__ wagg,
                                                     const float* __restrict__ bagg,
                                                     float* __restrict__ out) {
  __shared__ unsigned short sA[64 * 256];   // 32KB fused bf16 (swizzled)
  __shared__ unsigned short sM[64 * 256];   // 32KB mid   bf16 (swizzled)
  __shared__ float redS[4][64], redQ[4][64], redC[4][64];
  __shared__ float sSc[64];

  const int lane = threadIdx.x & 63, wid = threadIdx.x >> 6;
  const int lq = lane & 15, hi = lane >> 4;
  const int b = blockIdx.x / 192;
  const int u0 = (blockIdx.x % 192) * 16;

  const unsigned short* fuB = (const unsigned short*)(wsb + oFu);
  const unsigned short* Wm = (const unsigned short*)(wsb + oWm);
  const unsigned short* Wo = (const unsigned short*)(wsb + oWo);

  // ---- stage fused rows (4 modes x 16 u) -> sA ----
  {
    int t = threadIdx.x;
#pragma unroll
    for (int j = 0; j < 8; ++j) {
      int i = j * 256 + t;             // chunk index over [64 rows][32 chunks]
      int row = i >> 5, c = i & 31;
      int m = row >> 4, du = row & 15;
      bf16x8 v = *(const bf16x8*)(fuB + ((size_t)(b * 4 + m) * 3072 + u0 + du) * 256 + c * 8);
      *(bf16x8*)&sA[row * 256 + ((c ^ (row & 7)) << 3)] = v;
    }
  }
  __syncthreads();

  const int n0 = wid * 64;
  const int rowb = hi * 4;

  // ---- GEMM1: fused @ Wm^T (64 rows, this wave's 64 cols) ----
  f32x4 acc1[4][4];
#pragma unroll
  for (int rg = 0; rg < 4; ++rg)
#pragma unroll
    for (int bt = 0; bt < 4; ++bt) acc1[rg][bt] = (f32x4){0.f, 0.f, 0.f, 0.f};
#pragma unroll
  for (int ks = 0; ks < 8; ++ks) {
    bf16x8 a[4];
#pragma unroll
    for (int rg = 0; rg < 4; ++rg)
      a[rg] = *(const bf16x8*)&sA[(rg * 16 + lq) * 256 + (((ks * 4 + hi) ^ (lq & 7)) << 3)];
#pragma unroll
    for (int bt = 0; bt < 4; ++bt) {
      int n = n0 + bt * 16 + lq;
      bf16x8 bfr = *(const bf16x8*)(Wm + (size_t)n * 256 + ks * 32 + hi * 8);
#pragma unroll
      for (int rg = 0; rg < 4; ++rg) acc1[rg][bt] = MFMA16(a[rg], bfr, acc1[rg][bt]);
    }
  }
  // gelu -> sM
#pragma unroll
  for (int bt = 0; bt < 4; ++bt) {
    int n = n0 + bt * 16 + lq;
    float bb = bmid[n];
#pragma unroll
    for (int rg = 0; rg < 4; ++rg)
#pragma unroll
      for (int r = 0; r < 4; ++r) {
        float x = acc1[rg][bt][r] + bb;
        float g = 0.5f * x * (1.0f + erff(x * 0.7071067811865475f));
        int row = rg * 16 + rowb + r;
        sM[row * 256 + (((n >> 3) ^ (row & 7)) << 3) + (n & 7)] = f2bf(g);
      }
  }
  __syncthreads();

  // ---- GEMM2: mid @ Wo^T ----
  f32x4 acc2[4][4];
#pragma unroll
  for (int rg = 0; rg < 4; ++rg)
#pragma unroll
    for (int bt = 0; bt < 4; ++bt) acc2[rg][bt] = (f32x4){0.f, 0.f, 0.f, 0.f};
#pragma unroll
  for (int ks = 0; ks < 8; ++ks) {
    bf16x8 a[4];
#pragma unroll
    for (int rg = 0; rg < 4; ++rg)
      a[rg] = *(const bf16x8*)&sM[(rg * 16 + lq) * 256 + (((ks * 4 + hi) ^ (lq & 7)) << 3)];
#pragma unroll
    for (int bt = 0; bt < 4; ++bt) {
      int n = n0 + bt * 16 + lq;
      bf16x8 bfr = *(const bf16x8*)(Wo + (size_t)n * 256 + ks * 32 + hi * 8);
#pragma unroll
      for (int rg = 0; rg < 4; ++rg) acc2[rg][bt] = MFMA16(a[rg], bfr, acc2[rg][bt]);
    }
  }

  // ---- + b_out + residual; LN partial sums ----
  float sS[4][4], sQ[4][4];
#pragma unroll
  for (int rg = 0; rg < 4; ++rg)
#pragma unroll
    for (int r = 0; r < 4; ++r) { sS[rg][r] = 0.f; sQ[rg][r] = 0.f; }
#pragma unroll
  for (int bt = 0; bt < 4; ++bt) {
    int n = n0 + bt * 16 + lq;
    float bo = bout[n];
#pragma unroll
    for (int rg = 0; rg < 4; ++rg)
#pragma unroll
      for (int r = 0; r < 4; ++r) {
        int row = rg * 16 + rowb + r;
        float res = bf2f(sA[row * 256 + (((n >> 3) ^ (row & 7)) << 3) + (n & 7)]);
        float x = acc2[rg][bt][r] + bo + res;
        acc2[rg][bt][r] = x;
        sS[rg][r] += x;
        sQ[rg][r] += x * x;
      }
  }
#pragma unroll
  for (int rg = 0; rg < 4; ++rg)
#pragma unroll
    for (int r = 0; r < 4; ++r) {
#pragma unroll
      for (int off = 1; off < 16; off <<= 1) {
        sS[rg][r] += __shfl_xor(sS[rg][r], off);
        sQ[rg][r] += __shfl_xor(sQ[rg][r], off);
      }
    }
  if (lq == 0) {
#pragma unroll
    for (int rg = 0; rg < 4; ++rg)
#pragma unroll
      for (int r = 0; r < 4; ++r) {
        int row = rg * 16 + rowb + r;
        redS[wid][row] = sS[rg][r]; redQ[wid][row] = sQ[rg][r];
      }
  }
  __syncthreads();

  // ---- LN transform (in-place into acc2) + agg score partials ----
  float scp[4][4];
#pragma unroll
  for (int rg = 0; rg < 4; ++rg)
#pragma unroll
    for (int r = 0; r < 4; ++r) {
      int row = rg * 16 + rowb + r;
      float ts = redS[0][row] + redS[1][row] + redS[2][row] + redS[3][row];
      float tq = redQ[0][row] + redQ[1][row] + redQ[2][row] + redQ[3][row];
      float mean = ts * (1.0f / 256.0f);
      float var = tq * (1.0f / 256.0f) - mean * mean;
      float rs = rsqrtf(var + 1e-12f);
      float sc = 0.f;
#pragma unroll
      for (int bt = 0; bt < 4; ++bt) {
        int n = n0 + bt * 16 + lq;
        float o = (acc2[rg][bt][r] - mean) * rs * lng[n] + lnb[n];
        acc2[rg][bt][r] = o;
        sc += o * wagg[n];
      }
      scp[rg][r] = sc;
    }
#pragma unroll
  for (int rg = 0; rg < 4; ++rg)
#pragma unroll
    for (int r = 0; r < 4; ++r) {
#pragma unroll
      for (int off = 1; off < 16; off <<= 1) scp[rg][r] += __shfl_xor(scp[rg][r], off);
    }
  if (lq == 0) {
#pragma unroll
    for (int rg = 0; rg < 4; ++rg)
#pragma unroll
      for (int r = 0; r < 4; ++r) redC[wid][rg * 16 + rowb + r] = scp[rg][r];
  }
  __syncthreads();

  if (threadIdx.x < 64) {
    int t = threadIdx.x;
    sSc[t] = redC[0][t] + redC[1][t] + redC[2][t] + redC[3][t] + bagg[0];
  }
  __syncthreads();

  // ---- mode softmax + weighted sum (all in-register across rg) ----
  float wmode[4][4];   // [r][m]
#pragma unroll
  for (int r = 0; r < 4; ++r) {
    int du = rowb + r;
    float s0 = sSc[du], s1 = sSc[16 + du], s2 = sSc[32 + du], s3 = sSc[48 + du];
    float mx = fmaxf(fmaxf(s0, s1), fmaxf(s2, s3));
    float e0 = __builtin_amdgcn_exp2f((s0 - mx) * 1.44269504f);
    float e1 = __builtin_amdgcn_exp2f((s1 - mx) * 1.44269504f);
    float e2 = __builtin_amdgcn_exp2f((s2 - mx) * 1.44269504f);
    float e3 = __builtin_amdgcn_exp2f((s3 - mx) * 1.44269504f);
    float inv = 1.0f / (e0 + e1 + e2 + e3);
    wmode[r][0] = e0 * inv; wmode[r][1] = e1 * inv;
    wmode[r][2] = e2 * inv; wmode[r][3] = e3 * inv;
  }
#pragma unroll
  for (int bt = 0; bt < 4; ++bt) {
    int n = n0 + bt * 16 + lq;
#pragma unroll
    for (int r = 0; r < 4; ++r) {
      int du = rowb + r;
      float val = wmode[r][0] * acc2[0][bt][r] + wmode[r][1] * acc2[1][bt][r]
                + wmode[r][2] * acc2[2][bt][r] + wmode[r][3] * acc2[3][bt][r];
      out[((size_t)(b * 3072 + u0 + du)) * 256 + n] = val;
    }
  }
}

// ================= launcher =================
extern "C" void kernel_launch(void* const* d_in, const int* in_sizes, int n_in,
                              void* d_out, int out_size, void* d_ws, size_t ws_size,
                              hipStream_t stream) {
  const float* q  = (const float*)d_in[0];
  const float* k  = (const float*)d_in[1];
  const float* wq = (const float*)d_in[2];
  const float* wv = (const float*)d_in[3];
  const float* bv = (const float*)d_in[4];
  const float* wm = (const float*)d_in[5];
  const float* bm = (const float*)d_in[6];
  const float* wo = (const float*)d_in[7];
  const float* bo = (const float*)d_in[8];
  const float* lg = (const float*)d_in[9];
  const float* lb = (const float*)d_in[10];
  const float* wa = (const float*)d_in[11];
  const float* ba = (const float*)d_in[12];
  char* wsb = (char*)d_ws;

  cvt_kernel<<<3520, 256, 0, stream>>>(q, k, wq, wv, wm, wo, (unsigned short*)wsb);
  proj_kernel<<<2304, 256, 0, stream>>>(bv, wsb);
  attn_kernel<<<384, 128, 0, stream>>>(wsb);
  ffn_kernel<<<384, 256, 0, stream>>>(wsb, bm, bo, lg, lb, wa, ba, (float*)d_out);
}

// Round 4
// 196.848 us; speedup vs baseline: 2.1780x; 1.8203x over previous
//
#include <hip/hip_runtime.h>
#include <hip/hip_bf16.h>
#include <cstdint>
#include <cstddef>

// ---------------- types ----------------
typedef __attribute__((ext_vector_type(8))) short     bf16x8;
typedef __attribute__((ext_vector_type(4))) float     f32x4;
typedef __attribute__((ext_vector_type(4))) unsigned short u16x4;

using as1_void = __attribute__((address_space(1))) void;
using as3_void = __attribute__((address_space(3))) void;

#define MFMA16(a,b,c) __builtin_amdgcn_mfma_f32_16x16x32_bf16((a),(b),(c),0,0,0)

__device__ __forceinline__ unsigned short f2bf(float f) {
  union { float f; unsigned u; } v; v.f = f;
  unsigned r = v.u + 0x7fffu + ((v.u >> 16) & 1u);
  return (unsigned short)(r >> 16);
}
__device__ __forceinline__ float bf2f(unsigned short h) {
  union { unsigned u; float f; } v; v.u = ((unsigned)h) << 16; return v.f;
}

__device__ __forceinline__ void gload16(const void* g, void* l) {
  __builtin_amdgcn_global_load_lds((const as1_void*)g, (as3_void*)l, 16, 0, 0);
}

// ---------------- problem constants ----------------
// B=2, U1=U2=3072, IF=256, FD=256, M=4, D=64
constexpr size_t oXq  = 0;                       // bf16 [2*3072*256]
constexpr size_t oXk  = oXq + 1572864ull * 2;    // bf16 [2*3072*256]
constexpr size_t oWq  = oXk + 1572864ull * 2;    // bf16 [256*256]
constexpr size_t oWv  = oWq + 65536ull   * 2;    // bf16 [1024*256]
constexpr size_t oWm  = oWv + 262144ull  * 2;    // bf16 [256*256]
constexpr size_t oWo  = oWm + 65536ull   * 2;    // bf16 [256*256]
constexpr size_t oQb  = oWo + 65536ull   * 2;    // bf16 [8][3072][64]  (q/8)
constexpr size_t oKb  = oQb + 1572864ull * 2;    // bf16 [8][3072][64]
constexpr size_t oVb  = oKb + 1572864ull * 2;    // bf16 [8][256][3072] (V^T)
constexpr size_t oPa  = oVb + 6291456ull * 2;    // f32  [2][8][3072][256] O partials
constexpr size_t oMl  = oPa + 12582912ull * 4;   // f32  [2][8][3072][2]  (m,l)

// ================= kernel 1: f32 -> bf16 conversion of inputs =================
__global__ __launch_bounds__(256) void cvt_kernel(
    const float* __restrict__ q, const float* __restrict__ k,
    const float* __restrict__ wq, const float* __restrict__ wv,
    const float* __restrict__ wm, const float* __restrict__ wo,
    unsigned short* __restrict__ ws) {
  int i4 = (blockIdx.x * 256 + threadIdx.x) * 4;
  const float* src; int local;
  if (i4 < 1572864)       { src = q;  local = i4; }
  else if (i4 < 3145728)  { src = k;  local = i4 - 1572864; }
  else if (i4 < 3211264)  { src = wq; local = i4 - 3145728; }
  else if (i4 < 3473408)  { src = wv; local = i4 - 3211264; }
  else if (i4 < 3538944)  { src = wm; local = i4 - 3473408; }
  else                    { src = wo; local = i4 - 3538944; }
  f32x4 v = *(const f32x4*)(src + local);
  u16x4 o;
  o.x = f2bf(v.x); o.y = f2bf(v.y); o.z = f2bf(v.z); o.w = f2bf(v.w);
  *(u16x4*)(ws + i4) = o;
}

// ================= kernel 2: projections q,k,v =================
__global__ __launch_bounds__(256) void proj_kernel(const float* __restrict__ bv,
                                                   char* __restrict__ wsb) {
  int lane = threadIdx.x & 63, wid = threadIdx.x >> 6;
  int rowblk = blockIdx.x % 384;
  int ny = blockIdx.x / 384;
  int r0 = rowblk * 16;

  const unsigned short* X = (const unsigned short*)(wsb + (ny == 0 ? oXq : oXk));
  const unsigned short* W;
  if (ny <= 1) W = (const unsigned short*)(wsb + oWq);
  else         W = (const unsigned short*)(wsb + oWv) + (size_t)(ny - 2) * 256 * 256;

  int arow = r0 + (lane & 15);
  const unsigned short* Xp = X + (size_t)arow * 256 + ((lane >> 4) * 8);
  int n0 = wid * 64;

  f32x4 acc[4];
#pragma unroll
  for (int bt = 0; bt < 4; ++bt) acc[bt] = (f32x4){0.f, 0.f, 0.f, 0.f};

#pragma unroll
  for (int ks = 0; ks < 8; ++ks) {
    bf16x8 af = *(const bf16x8*)(Xp + ks * 32);
#pragma unroll
    for (int bt = 0; bt < 4; ++bt) {
      int n = n0 + bt * 16 + (lane & 15);
      bf16x8 bf = *(const bf16x8*)(W + (size_t)n * 256 + ks * 32 + ((lane >> 4) * 8));
      acc[bt] = MFMA16(af, bf, acc[bt]);
    }
  }

  int b = r0 / 3072, u0 = r0 % 3072;
  int ubase = u0 + ((lane >> 4) * 4);

  if (ny <= 1) {
    unsigned short* outp = (unsigned short*)(wsb + (ny == 0 ? oQb : oKb));
    float scale = (ny == 0) ? 0.125f : 1.0f;
    int m = wid;
#pragma unroll
    for (int bt = 0; bt < 4; ++bt) {
      int d = bt * 16 + (lane & 15);
#pragma unroll
      for (int r = 0; r < 4; ++r) {
        outp[((size_t)(b * 4 + m) * 3072 + (ubase + r)) * 64 + d] = f2bf(acc[bt][r] * scale);
      }
    }
  } else {
    unsigned short* vbT = (unsigned short*)(wsb + oVb);
    int mchunk = ny - 2;
#pragma unroll
    for (int bt = 0; bt < 4; ++bt) {
      int f = n0 + bt * 16 + (lane & 15);
      float bias = bv[mchunk * 256 + f];
      u16x4 pk;
#pragma unroll
      for (int r = 0; r < 4; ++r) pk[r] = f2bf(acc[bt][r] + bias);
      *(u16x4*)(vbT + ((size_t)(b * 4 + mchunk) * 256 + f) * 3072 + ubase) = pk;
    }
  }
}

// ================= kernel 3: flash attention (f-half split + kv-split) =======
// grid 768 x 256 (4 waves): bm = bid&7 (XCD pin), z = bid>>3: qt = z>>1 (64 q),
// kvh = z&1 (kv half: 24 tiles of 64).
// Wave w: fh = w>>1 (PV f-half), gp = w&1 (q-pair). Waves (0,2) and (1,3)
// redundantly compute identical QK^T+softmax for their 2 q-groups (no barrier,
// no idle waves); P written duplicate-identical into shared sP[gp][g].
// V-frag reused across the 2 q-groups (halves LDS V reads).
// Epilogue: partial O/l (f32) + (m,l) per q-row; exact combine fused into ffn.
__global__ __launch_bounds__(256, 3) void attn_kernel(char* __restrict__ wsb) {
  __shared__ unsigned short sK[64 * 64];        // 8KB  [kv][d]  chunk-swizzled
  __shared__ unsigned short sV[256 * 64];       // 32KB [f][kv]  chunk-swizzled
  __shared__ unsigned short sP[2][2][16 * 64];  // 8KB  [gp][g]  P^T

  const int lane = threadIdx.x & 63, wid = threadIdx.x >> 6;
  const int lq = lane & 15, hi = lane >> 4;
  const int lr3 = lane >> 3, lc3 = lane & 7;
  const int fh = wid >> 1, gp = wid & 1;
  const int bm = blockIdx.x & 7;
  const int z = blockIdx.x >> 3;
  const int qt = z >> 1, kvh = z & 1;
  const int q0 = qt * 64;
  const int key = lq & 7;

  const unsigned short* qb = (const unsigned short*)(wsb + oQb) + (size_t)bm * 3072 * 64;
  const unsigned short* kb = (const unsigned short*)(wsb + oKb) + (size_t)bm * 3072 * 64;
  const unsigned short* vb = (const unsigned short*)(wsb + oVb) + (size_t)bm * 256 * 3072;

  // persistent Q B-frags for this wave's 2 q-groups
  bf16x8 qf[2][2];
#pragma unroll
  for (int g = 0; g < 2; ++g) {
    const unsigned short* qp = qb + (size_t)(q0 + gp * 32 + g * 16 + lq) * 64 + hi * 8;
    qf[g][0] = *(const bf16x8*)(qp);
    qf[g][1] = *(const bf16x8*)(qp + 32);
  }

  f32x4 acc[2][8];
#pragma unroll
  for (int g = 0; g < 2; ++g)
#pragma unroll
    for (int ft = 0; ft < 8; ++ft) acc[g][ft] = (f32x4){0.f, 0.f, 0.f, 0.f};
  float mrun[2] = {-1e30f, -1e30f}, lrun[2] = {0.f, 0.f};

  for (int kt = 0; kt < 24; ++kt) {
    const int kv0 = kvh * 1536 + kt * 64;

    // ---- stage K tile: 8 x 1KB chunks (this wave: 2) ----
#pragma unroll
    for (int i = 0; i < 2; ++i) {
      int ch = wid * 2 + i;
      int r = ch * 8 + lr3;
      int cs = lc3 ^ (r & 7);
      gload16(kb + (size_t)(kv0 + r) * 64 + cs * 8, &sK[ch * 512]);
    }
    // ---- stage V^T tile: 32 chunks (this wave: 8) ----
#pragma unroll
    for (int i = 0; i < 8; ++i) {
      int ch = i * 4 + wid;
      int f = ch * 8 + lr3;
      int cs = lc3 ^ (f & 7);
      gload16(vb + (size_t)f * 3072 + kv0 + cs * 8, &sV[ch * 512]);
    }
    __syncthreads();   // staging complete

    // ---- K A-frags ----
    bf16x8 kc[4][2];
#pragma unroll
    for (int t = 0; t < 4; ++t) {
      const unsigned short* kr = &sK[(t * 16 + lq) * 64];
      kc[t][0] = *(const bf16x8*)(kr + ((hi ^ key) * 8));
      kc[t][1] = *(const bf16x8*)(kr + (((hi + 4) ^ key) * 8));
    }

    // ---- QK^T both groups: s[g][t][r] = S[q][kv0 + t*16 + hi*4 + r] ----
    f32x4 s[2][4];
#pragma unroll
    for (int g = 0; g < 2; ++g)
#pragma unroll
      for (int t = 0; t < 4; ++t) {
        f32x4 zz = (f32x4){0.f, 0.f, 0.f, 0.f};
        zz = MFMA16(kc[t][0], qf[g][0], zz);
        zz = MFMA16(kc[t][1], qf[g][1], zz);
        s[g][t] = zz;
      }

    // ---- lane-local online softmax per group ----
    bf16x8 pb[2][2];
#pragma unroll
    for (int g = 0; g < 2; ++g) {
      float pmax = s[g][0][0];
#pragma unroll
      for (int t = 0; t < 4; ++t)
#pragma unroll
        for (int r = 0; r < 4; ++r) pmax = fmaxf(pmax, s[g][t][r]);
      pmax = fmaxf(pmax, __shfl_xor(pmax, 16));
      pmax = fmaxf(pmax, __shfl_xor(pmax, 32));

      if (__any(pmax > mrun[g] + 8.0f)) {   // defer-max rescale
        float mnew = fmaxf(mrun[g], pmax);
        float cr = __builtin_amdgcn_exp2f((mrun[g] - mnew) * 1.44269504f);
#pragma unroll
        for (int ft = 0; ft < 8; ++ft) {
          acc[g][ft][0] *= cr; acc[g][ft][1] *= cr;
          acc[g][ft][2] *= cr; acc[g][ft][3] *= cr;
        }
        lrun[g] *= cr; mrun[g] = mnew;
      }

      const float mk = mrun[g] * 1.44269504f;
      float psum = 0.f;
#pragma unroll
      for (int t = 0; t < 4; ++t)
#pragma unroll
        for (int r = 0; r < 4; ++r) {
          float p = __builtin_amdgcn_exp2f(s[g][t][r] * 1.44269504f - mk);
          s[g][t][r] = p; psum += p;
        }
      psum += __shfl_xor(psum, 16);
      psum += __shfl_xor(psum, 32);
      lrun[g] += psum;

      // pack P^T into shared sP[gp][g] (fh-pair writes identical bytes: benign)
      char* myP = (char*)&sP[gp][g][0];
#pragma unroll
      for (int t = 0; t < 4; ++t) {
        unsigned w0 = (unsigned)f2bf(s[g][t][0]) | ((unsigned)f2bf(s[g][t][1]) << 16);
        unsigned w1 = (unsigned)f2bf(s[g][t][2]) | ((unsigned)f2bf(s[g][t][3]) << 16);
        int c = (2 * t + (hi >> 1)) ^ key;
        *(uint2*)(myP + lq * 128 + (c << 4) + ((hi & 1) << 3)) = make_uint2(w0, w1);
      }
      pb[g][0] = *(const bf16x8*)(myP + lq * 128 + ((hi ^ key) << 4));
      pb[g][1] = *(const bf16x8*)(myP + lq * 128 + (((4 + hi) ^ key) << 4));
    }

    // ---- PV on this wave's f-half (V-frag reused for both groups) ----
    __builtin_amdgcn_s_setprio(1);
#pragma unroll
    for (int ft = 0; ft < 8; ++ft) {
      const unsigned short* vr = &sV[(fh * 128 + ft * 16 + lq) * 64];
      bf16x8 vf0 = *(const bf16x8*)(vr + ((hi ^ key) * 8));
      bf16x8 vf1 = *(const bf16x8*)(vr + (((4 + hi) ^ key) * 8));
      acc[0][ft] = MFMA16(vf0, pb[0][0], acc[0][ft]);
      acc[0][ft] = MFMA16(vf1, pb[0][1], acc[0][ft]);
      acc[1][ft] = MFMA16(vf0, pb[1][0], acc[1][ft]);
      acc[1][ft] = MFMA16(vf1, pb[1][1], acc[1][ft]);
    }
    __builtin_amdgcn_s_setprio(0);
    __syncthreads();   // all reads done before next stage
  }

  // ---- epilogue: partial O/l (f32) + (m,l) ----
  float* pa = (float*)(wsb + oPa) + (size_t)(kvh * 8 + bm) * 3072 * 256;
#pragma unroll
  for (int g = 0; g < 2; ++g) {
    const float inv = 1.0f / lrun[g];
    float* orow = pa + (size_t)(q0 + gp * 32 + g * 16 + lq) * 256 + fh * 128 + hi * 4;
#pragma unroll
    for (int ft = 0; ft < 8; ++ft) {
      f32x4 o = acc[g][ft];
      o[0] *= inv; o[1] *= inv; o[2] *= inv; o[3] *= inv;
      *(f32x4*)(orow + ft * 16) = o;
    }
  }
  if (wid < 2 && hi == 0) {   // fh==0 waves cover gp 0,1
    float* ml = (float*)(wsb + oMl);
#pragma unroll
    for (int g = 0; g < 2; ++g) {
      size_t qi = (size_t)(kvh * 8 + bm) * 3072 + q0 + gp * 32 + g * 16 + lq;
      *(float2*)(ml + qi * 2) = make_float2(mrun[g], lrun[g]);
    }
  }
}

// ================= kernel 4: combine + FFN + LN + mode aggregation ===========
// grid 384 = 2 b x 192 u-blocks of 16. Rows: row = m*16 + du (64 rows).
// Stage: exact (m,l)-weighted combine of the two kv-half partials -> sA bf16.
// Then GEMM1+gelu -> GEMM2+residual+LN -> agg scores -> mode softmax -> out.
__global__ __launch_bounds__(256, 2) void ffn_kernel(char* __restrict__ wsb,
                                                     const float* __restrict__ bmid,
                                                     const float* __restrict__ bout,
                                                     const float* __restrict__ lng,
                                                     const float* __restrict__ lnb,
                                                     const float* __restrict__ wagg,
                                                     const float* __restrict__ bagg,
                                                     float* __restrict__ out) {
  __shared__ unsigned short sA[64 * 256];   // 32KB combined fused bf16 (swizzled)
  __shared__ unsigned short sM[64 * 256];   // 32KB mid bf16 (swizzled)
  __shared__ float redS[4][64], redQ[4][64], redC[4][64];
  __shared__ float sSc[64];
  __shared__ float sW0[64], sW1[64];

  const int lane = threadIdx.x & 63, wid = threadIdx.x >> 6;
  const int lq = lane & 15, hi = lane >> 4;
  const int b = blockIdx.x / 192;
  const int u0 = (blockIdx.x % 192) * 16;

  const unsigned short* Wm = (const unsigned short*)(wsb + oWm);
  const unsigned short* Wo = (const unsigned short*)(wsb + oWo);
  const float* pa = (const float*)(wsb + oPa);
  const float* mlb = (const float*)(wsb + oMl);

  // ---- combine weights per row ----
  if (threadIdx.x < 64) {
    int m = threadIdx.x >> 4, du = threadIdx.x & 15;
    size_t qi = (size_t)(b * 4 + m) * 3072 + u0 + du;
    float2 ml0 = *(const float2*)(mlb + qi * 2);
    float2 ml1 = *(const float2*)(mlb + (qi + 8ull * 3072) * 2);
    float M = fmaxf(ml0.x, ml1.x);
    float e0 = ml0.y * __builtin_amdgcn_exp2f((ml0.x - M) * 1.44269504f);
    float e1 = ml1.y * __builtin_amdgcn_exp2f((ml1.x - M) * 1.44269504f);
    float inv = 1.0f / (e0 + e1);
    sW0[threadIdx.x] = e0 * inv;
    sW1[threadIdx.x] = e1 * inv;
  }
  __syncthreads();

  // ---- stage combined fused rows -> sA (bf16, swizzled) ----
  {
    int t = threadIdx.x;
#pragma unroll
    for (int j = 0; j < 8; ++j) {
      int i = j * 256 + t;             // chunk index over [64 rows][32 chunks]
      int row = i >> 5, c = i & 31;
      int m = row >> 4, du = row & 15;
      const float* p0 = pa + ((size_t)(b * 4 + m) * 3072 + u0 + du) * 256 + c * 8;
      const float* p1 = p0 + 8ull * 3072 * 256;
      f32x4 a0 = *(const f32x4*)(p0);
      f32x4 a1 = *(const f32x4*)(p0 + 4);
      f32x4 b0 = *(const f32x4*)(p1);
      f32x4 b1 = *(const f32x4*)(p1 + 4);
      float w0 = sW0[row], w1 = sW1[row];
      u16x4 oA, oB;
#pragma unroll
      for (int e = 0; e < 4; ++e) {
        oA[e] = f2bf(w0 * a0[e] + w1 * b0[e]);
        oB[e] = f2bf(w0 * a1[e] + w1 * b1[e]);
      }
      unsigned short* dst = &sA[row * 256 + ((c ^ (row & 7)) << 3)];
      *(u16x4*)(dst) = oA;
      *(u16x4*)(dst + 4) = oB;
    }
  }
  __syncthreads();

  const int n0 = wid * 64;
  const int rowb = hi * 4;

  // ---- GEMM1: fused @ Wm^T ----
  f32x4 acc1[4][4];
#pragma unroll
  for (int rg = 0; rg < 4; ++rg)
#pragma unroll
    for (int bt = 0; bt < 4; ++bt) acc1[rg][bt] = (f32x4){0.f, 0.f, 0.f, 0.f};
#pragma unroll
  for (int ks = 0; ks < 8; ++ks) {
    bf16x8 a[4];
#pragma unroll
    for (int rg = 0; rg < 4; ++rg)
      a[rg] = *(const bf16x8*)&sA[(rg * 16 + lq) * 256 + (((ks * 4 + hi) ^ (lq & 7)) << 3)];
#pragma unroll
    for (int bt = 0; bt < 4; ++bt) {
      int n = n0 + bt * 16 + lq;
      bf16x8 bfr = *(const bf16x8*)(Wm + (size_t)n * 256 + ks * 32 + hi * 8);
#pragma unroll
      for (int rg = 0; rg < 4; ++rg) acc1[rg][bt] = MFMA16(a[rg], bfr, acc1[rg][bt]);
    }
  }
  // gelu -> sM
#pragma unroll
  for (int bt = 0; bt < 4; ++bt) {
    int n = n0 + bt * 16 + lq;
    float bb = bmid[n];
#pragma unroll
    for (int rg = 0; rg < 4; ++rg)
#pragma unroll
      for (int r = 0; r < 4; ++r) {
        float x = acc1[rg][bt][r] + bb;
        float g = 0.5f * x * (1.0f + erff(x * 0.7071067811865475f));
        int row = rg * 16 + rowb + r;
        sM[row * 256 + (((n >> 3) ^ (row & 7)) << 3) + (n & 7)] = f2bf(g);
      }
  }
  __syncthreads();

  // ---- GEMM2: mid @ Wo^T ----
  f32x4 acc2[4][4];
#pragma unroll
  for (int rg = 0; rg < 4; ++rg)
#pragma unroll
    for (int bt = 0; bt < 4; ++bt) acc2[rg][bt] = (f32x4){0.f, 0.f, 0.f, 0.f};
#pragma unroll
  for (int ks = 0; ks < 8; ++ks) {
    bf16x8 a[4];
#pragma unroll
    for (int rg = 0; rg < 4; ++rg)
      a[rg] = *(const bf16x8*)&sM[(rg * 16 + lq) * 256 + (((ks * 4 + hi) ^ (lq & 7)) << 3)];
#pragma unroll
    for (int bt = 0; bt < 4; ++bt) {
      int n = n0 + bt * 16 + lq;
      bf16x8 bfr = *(const bf16x8*)(Wo + (size_t)n * 256 + ks * 32 + hi * 8);
#pragma unroll
      for (int rg = 0; rg < 4; ++rg) acc2[rg][bt] = MFMA16(a[rg], bfr, acc2[rg][bt]);
    }
  }

  // ---- + b_out + residual; LN partial sums ----
  float sS[4][4], sQ[4][4];
#pragma unroll
  for (int rg = 0; rg < 4; ++rg)
#pragma unroll
    for (int r = 0; r < 4; ++r) { sS[rg][r] = 0.f; sQ[rg][r] = 0.f; }
#pragma unroll
  for (int bt = 0; bt < 4; ++bt) {
    int n = n0 + bt * 16 + lq;
    float bo = bout[n];
#pragma unroll
    for (int rg = 0; rg < 4; ++rg)
#pragma unroll
      for (int r = 0; r < 4; ++r) {
        int row = rg * 16 + rowb + r;
        float res = bf2f(sA[row * 256 + (((n >> 3) ^ (row & 7)) << 3) + (n & 7)]);
        float x = acc2[rg][bt][r] + bo + res;
        acc2[rg][bt][r] = x;
        sS[rg][r] += x;
        sQ[rg][r] += x * x;
      }
  }
#pragma unroll
  for (int rg = 0; rg < 4; ++rg)
#pragma unroll
    for (int r = 0; r < 4; ++r) {
#pragma unroll
      for (int off = 1; off < 16; off <<= 1) {
        sS[rg][r] += __shfl_xor(sS[rg][r], off);
        sQ[rg][r] += __shfl_xor(sQ[rg][r], off);
      }
    }
  if (lq == 0) {
#pragma unroll
    for (int rg = 0; rg < 4; ++rg)
#pragma unroll
      for (int r = 0; r < 4; ++r) {
        int row = rg * 16 + rowb + r;
        redS[wid][row] = sS[rg][r]; redQ[wid][row] = sQ[rg][r];
      }
  }
  __syncthreads();

  // ---- LN transform (in-place into acc2) + agg score partials ----
  float scp[4][4];
#pragma unroll
  for (int rg = 0; rg < 4; ++rg)
#pragma unroll
    for (int r = 0; r < 4; ++r) {
      int row = rg * 16 + rowb + r;
      float ts = redS[0][row] + redS[1][row] + redS[2][row] + redS[3][row];
      float tq = redQ[0][row] + redQ[1][row] + redQ[2][row] + redQ[3][row];
      float mean = ts * (1.0f / 256.0f);
      float var = tq * (1.0f / 256.0f) - mean * mean;
      float rs = rsqrtf(var + 1e-12f);
      float sc = 0.f;
#pragma unroll
      for (int bt = 0; bt < 4; ++bt) {
        int n = n0 + bt * 16 + lq;
        float o = (acc2[rg][bt][r] - mean) * rs * lng[n] + lnb[n];
        acc2[rg][bt][r] = o;
        sc += o * wagg[n];
      }
      scp[rg][r] = sc;
    }
#pragma unroll
  for (int rg = 0; rg < 4; ++rg)
#pragma unroll
    for (int r = 0; r < 4; ++r) {
#pragma unroll
      for (int off = 1; off < 16; off <<= 1) scp[rg][r] += __shfl_xor(scp[rg][r], off);
    }
  if (lq == 0) {
#pragma unroll
    for (int rg = 0; rg < 4; ++rg)
#pragma unroll
      for (int r = 0; r < 4; ++r) redC[wid][rg * 16 + rowb + r] = scp[rg][r];
  }
  __syncthreads();

  if (threadIdx.x < 64) {
    int t = threadIdx.x;
    sSc[t] = redC[0][t] + redC[1][t] + redC[2][t] + redC[3][t] + bagg[0];
  }
  __syncthreads();

  // ---- mode softmax + weighted sum ----
  float wmode[4][4];   // [r][m]
#pragma unroll
  for (int r = 0; r < 4; ++r) {
    int du = rowb + r;
    float s0 = sSc[du], s1 = sSc[16 + du], s2 = sSc[32 + du], s3 = sSc[48 + du];
    float mx = fmaxf(fmaxf(s0, s1), fmaxf(s2, s3));
    float e0 = __builtin_amdgcn_exp2f((s0 - mx) * 1.44269504f);
    float e1 = __builtin_amdgcn_exp2f((s1 - mx) * 1.44269504f);
    float e2 = __builtin_amdgcn_exp2f((s2 - mx) * 1.44269504f);
    float e3 = __builtin_amdgcn_exp2f((s3 - mx) * 1.44269504f);
    float inv = 1.0f / (e0 + e1 + e2 + e3);
    wmode[r][0] = e0 * inv; wmode[r][1] = e1 * inv;
    wmode[r][2] = e2 * inv; wmode[r][3] = e3 * inv;
  }
#pragma unroll
  for (int bt = 0; bt < 4; ++bt) {
    int n = n0 + bt * 16 + lq;
#pragma unroll
    for (int r = 0; r < 4; ++r) {
      int du = rowb + r;
      float val = wmode[r][0] * acc2[0][bt][r] + wmode[r][1] * acc2[1][bt][r]
                + wmode[r][2] * acc2[2][bt][r] + wmode[r][3] * acc2[3][bt][r];
      out[((size_t)(b * 3072 + u0 + du)) * 256 + n] = val;
    }
  }
}

// ================= launcher =================
extern "C" void kernel_launch(void* const* d_in, const int* in_sizes, int n_in,
                              void* d_out, int out_size, void* d_ws, size_t ws_size,
                              hipStream_t stream) {
  const float* q  = (const float*)d_in[0];
  const float* k  = (const float*)d_in[1];
  const float* wq = (const float*)d_in[2];
  const float* wv = (const float*)d_in[3];
  const float* bv = (const float*)d_in[4];
  const float* wm = (const float*)d_in[5];
  const float* bm = (const float*)d_in[6];
  const float* wo = (const float*)d_in[7];
  const float* bo = (const float*)d_in[8];
  const float* lg = (const float*)d_in[9];
  const float* lb = (const float*)d_in[10];
  const float* wa = (const float*)d_in[11];
  const float* ba = (const float*)d_in[12];
  char* wsb = (char*)d_ws;

  cvt_kernel<<<3520, 256, 0, stream>>>(q, k, wq, wv, wm, wo, (unsigned short*)wsb);
  proj_kernel<<<2304, 256, 0, stream>>>(bv, wsb);
  attn_kernel<<<768, 256, 0, stream>>>(wsb);
  ffn_kernel<<<384, 256, 0, stream>>>(wsb, bm, bo, lg, lb, wa, ba, (float*)d_out);
}

// Round 5
// 151.838 us; speedup vs baseline: 2.8236x; 1.2964x over previous
//
#include <hip/hip_runtime.h>
#include <hip/hip_bf16.h>
#include <cstdint>
#include <cstddef>

// ---------------- types ----------------
typedef __attribute__((ext_vector_type(8))) short     bf16x8;
typedef __attribute__((ext_vector_type(4))) float     f32x4;
typedef __attribute__((ext_vector_type(4))) unsigned short u16x4;

using as1_void = __attribute__((address_space(1))) void;
using as3_void = __attribute__((address_space(3))) void;

#define MFMA16(a,b,c) __builtin_amdgcn_mfma_f32_16x16x32_bf16((a),(b),(c),0,0,0)

__device__ __forceinline__ unsigned short f2bf(float f) {
  union { float f; unsigned u; } v; v.f = f;
  unsigned r = v.u + 0x7fffu + ((v.u >> 16) & 1u);
  return (unsigned short)(r >> 16);
}
__device__ __forceinline__ float bf2f(unsigned short h) {
  union { unsigned u; float f; } v; v.u = ((unsigned)h) << 16; return v.f;
}
__device__ __forceinline__ unsigned cvt_pk_bf16(float lo, float hi) {
  unsigned r;
  asm volatile("v_cvt_pk_bf16_f32 %0, %1, %2" : "=v"(r) : "v"(lo), "v"(hi));
  return r;
}

__device__ __forceinline__ void gload16(const void* g, void* l) {
  __builtin_amdgcn_global_load_lds((const as1_void*)g, (as3_void*)l, 16, 0, 0);
}

// ---------------- problem constants ----------------
// B=2, U1=U2=3072, IF=256, FD=256, M=4, D=64
constexpr size_t oXq  = 0;                       // bf16 [2*3072*256]
constexpr size_t oXk  = oXq + 1572864ull * 2;    // bf16 [2*3072*256]
constexpr size_t oWq  = oXk + 1572864ull * 2;    // bf16 [256*256]
constexpr size_t oWv  = oWq + 65536ull   * 2;    // bf16 [1024*256]
constexpr size_t oWm  = oWv + 262144ull  * 2;    // bf16 [256*256]
constexpr size_t oWo  = oWm + 65536ull   * 2;    // bf16 [256*256]
constexpr size_t oQb  = oWo + 65536ull   * 2;    // bf16 [8][3072][64]  (q/8)
constexpr size_t oKb  = oQb + 1572864ull * 2;    // bf16 [8][3072][64]
constexpr size_t oVb  = oKb + 1572864ull * 2;    // bf16 [8][256][3072] (V^T)
constexpr size_t oPa  = oVb + 6291456ull * 2;    // bf16 [2][8][3072][256] O partials
constexpr size_t oMl  = oPa + 12582912ull * 2;   // f32  [2][8][3072][2]  (m,l)

// ================= kernel 1: f32 -> bf16 conversion of inputs =================
__global__ __launch_bounds__(256) void cvt_kernel(
    const float* __restrict__ q, const float* __restrict__ k,
    const float* __restrict__ wq, const float* __restrict__ wv,
    const float* __restrict__ wm, const float* __restrict__ wo,
    unsigned short* __restrict__ ws) {
  int i4 = (blockIdx.x * 256 + threadIdx.x) * 4;
  const float* src; int local;
  if (i4 < 1572864)       { src = q;  local = i4; }
  else if (i4 < 3145728)  { src = k;  local = i4 - 1572864; }
  else if (i4 < 3211264)  { src = wq; local = i4 - 3145728; }
  else if (i4 < 3473408)  { src = wv; local = i4 - 3211264; }
  else if (i4 < 3538944)  { src = wm; local = i4 - 3473408; }
  else                    { src = wo; local = i4 - 3538944; }
  f32x4 v = *(const f32x4*)(src + local);
  u16x4 o;
  o.x = f2bf(v.x); o.y = f2bf(v.y); o.z = f2bf(v.z); o.w = f2bf(v.w);
  *(u16x4*)(ws + i4) = o;
}

// ================= kernel 2: projections q,k,v =================
__global__ __launch_bounds__(256) void proj_kernel(const float* __restrict__ bv,
                                                   char* __restrict__ wsb) {
  int lane = threadIdx.x & 63, wid = threadIdx.x >> 6;
  int rowblk = blockIdx.x % 384;
  int ny = blockIdx.x / 384;
  int r0 = rowblk * 16;

  const unsigned short* X = (const unsigned short*)(wsb + (ny == 0 ? oXq : oXk));
  const unsigned short* W;
  if (ny <= 1) W = (const unsigned short*)(wsb + oWq);
  else         W = (const unsigned short*)(wsb + oWv) + (size_t)(ny - 2) * 256 * 256;

  int arow = r0 + (lane & 15);
  const unsigned short* Xp = X + (size_t)arow * 256 + ((lane >> 4) * 8);
  int n0 = wid * 64;

  f32x4 acc[4];
#pragma unroll
  for (int bt = 0; bt < 4; ++bt) acc[bt] = (f32x4){0.f, 0.f, 0.f, 0.f};

#pragma unroll
  for (int ks = 0; ks < 8; ++ks) {
    bf16x8 af = *(const bf16x8*)(Xp + ks * 32);
#pragma unroll
    for (int bt = 0; bt < 4; ++bt) {
      int n = n0 + bt * 16 + (lane & 15);
      bf16x8 bf = *(const bf16x8*)(W + (size_t)n * 256 + ks * 32 + ((lane >> 4) * 8));
      acc[bt] = MFMA16(af, bf, acc[bt]);
    }
  }

  int b = r0 / 3072, u0 = r0 % 3072;
  int ubase = u0 + ((lane >> 4) * 4);

  if (ny <= 1) {
    unsigned short* outp = (unsigned short*)(wsb + (ny == 0 ? oQb : oKb));
    float scale = (ny == 0) ? 0.125f : 1.0f;
    int m = wid;
#pragma unroll
    for (int bt = 0; bt < 4; ++bt) {
      int d = bt * 16 + (lane & 15);
#pragma unroll
      for (int r = 0; r < 4; ++r) {
        outp[((size_t)(b * 4 + m) * 3072 + (ubase + r)) * 64 + d] = f2bf(acc[bt][r] * scale);
      }
    }
  } else {
    unsigned short* vbT = (unsigned short*)(wsb + oVb);
    int mchunk = ny - 2;
#pragma unroll
    for (int bt = 0; bt < 4; ++bt) {
      int f = n0 + bt * 16 + (lane & 15);
      float bias = bv[mchunk * 256 + f];
      u16x4 pk;
#pragma unroll
      for (int r = 0; r < 4; ++r) pk[r] = f2bf(acc[bt][r] + bias);
      *(u16x4*)(vbT + ((size_t)(b * 4 + mchunk) * 256 + f) * 3072 + ubase) = pk;
    }
  }
}

// ================= kernel 3: flash attention (dedup + counted vmcnt) =========
// grid 768 x 256 (4 waves): bm = bid&7 (XCD pin), z = bid>>3: qt = z>>1 (64 q),
// kvh = z&1 (kv half, 24 tiles of 64).
// Wave w: QK^T + lane-local online softmax for group g=w (16 q-rows), pack
// P^T (cvt_pk) into shared sP[w]. Then wave w = (fh=w>>1, gp=w&1) does PV for
// f-half fh over groups gp*2, gp*2+1 (V-frag reused x2).
// Barrier schedule per tile (raw s_barrier + counted waitcnt):
//   issue V(8) -> vmcnt(8) [K landed] bar1 -> QK/SM/pack (V lands under this)
//   -> vmcnt(0) lgkmcnt(0) bar2 -> issue K(t+1) -> rescale+PV -> bar3
__global__ __launch_bounds__(256, 3) void attn_kernel(char* __restrict__ wsb) {
  __shared__ unsigned short sK[64 * 64];        // 8KB  [kv][d]  chunk-swizzled
  __shared__ unsigned short sV[256 * 64];       // 32KB [f][kv]  chunk-swizzled
  __shared__ unsigned short sP[4][16 * 64];     // 8KB  [g]      P^T
  __shared__ float sCr[4];
  __shared__ float sInv[4][16];

  const int lane = threadIdx.x & 63, wid = threadIdx.x >> 6;
  const int lq = lane & 15, hi = lane >> 4;
  const int lr3 = lane >> 3, lc3 = lane & 7;
  const int fh = wid >> 1, gp = wid & 1;
  const int bm = blockIdx.x & 7;
  const int z = blockIdx.x >> 3;
  const int qt = z >> 1, kvh = z & 1;
  const int q0 = qt * 64;
  const int kvbase = kvh * 1536;
  const int key = lq & 7;

  const unsigned short* qb = (const unsigned short*)(wsb + oQb) + (size_t)bm * 3072 * 64;
  const unsigned short* kb = (const unsigned short*)(wsb + oKb) + (size_t)bm * 3072 * 64;
  const unsigned short* vb = (const unsigned short*)(wsb + oVb) + (size_t)bm * 256 * 3072;

  // persistent Q B-frags for this wave's group (q = q0 + wid*16 + lq)
  const unsigned short* qp = qb + (size_t)(q0 + wid * 16 + lq) * 64 + hi * 8;
  const bf16x8 qf0 = *(const bf16x8*)(qp);
  const bf16x8 qf1 = *(const bf16x8*)(qp + 32);
  asm volatile("s_waitcnt vmcnt(0)" ::: "memory");   // qf resident; vmcnt clean

  // staging pointers (bumped per tile)
  const unsigned short* pk[2];
  unsigned short* dk[2];
#pragma unroll
  for (int i = 0; i < 2; ++i) {
    int ch = wid * 2 + i;
    int r = ch * 8 + lr3;
    int cs = lc3 ^ (r & 7);
    pk[i] = kb + (size_t)(kvbase + r) * 64 + cs * 8;
    dk[i] = &sK[ch * 512];
  }
  const unsigned short* pv[8];
  unsigned short* dv[8];
#pragma unroll
  for (int i = 0; i < 8; ++i) {
    int ch = i * 4 + wid;
    int f = ch * 8 + lr3;
    int cs = lc3 ^ (f & 7);
    pv[i] = vb + (size_t)f * 3072 + kvbase + cs * 8;
    dv[i] = &sV[ch * 512];
  }

  f32x4 acc[2][8];
#pragma unroll
  for (int g = 0; g < 2; ++g)
#pragma unroll
    for (int ft = 0; ft < 8; ++ft) acc[g][ft] = (f32x4){0.f, 0.f, 0.f, 0.f};
  float mrun = -1e30f, lrun = 0.f;

  char* myP = (char*)&sP[wid][0];
  const int g0 = gp * 2, g1 = gp * 2 + 1;
  char* rP0 = (char*)&sP[g0][0];
  char* rP1 = (char*)&sP[g1][0];

  // prologue: issue K tile 0
  gload16(pk[0], dk[0]); gload16(pk[1], dk[1]);
  pk[0] += 4096; pk[1] += 4096;

  for (int kt = 0; kt < 24; ++kt) {
    // ---- issue V tile kt (8 chunks this wave) ----
#pragma unroll
    for (int i = 0; i < 8; ++i) { gload16(pv[i], dv[i]); pv[i] += 64; }

    asm volatile("s_waitcnt vmcnt(8)" ::: "memory");   // K landed (V in flight)
    __builtin_amdgcn_sched_barrier(0);
    __builtin_amdgcn_s_barrier();                       // bar1

    // ---- QK^T group w: s[t][r] = S[q=lq][t*16 + hi*4 + r] ----
    bf16x8 kc0[4], kc1[4];
#pragma unroll
    for (int t = 0; t < 4; ++t) {
      const unsigned short* kr = &sK[(t * 16 + lq) * 64];
      kc0[t] = *(const bf16x8*)(kr + ((hi ^ key) * 8));
      kc1[t] = *(const bf16x8*)(kr + (((hi + 4) ^ key) * 8));
    }
    f32x4 s[4];
#pragma unroll
    for (int t = 0; t < 4; ++t) {
      f32x4 zz = (f32x4){0.f, 0.f, 0.f, 0.f};
      zz = MFMA16(kc0[t], qf0, zz);
      zz = MFMA16(kc1[t], qf1, zz);
      s[t] = zz;
    }

    // ---- lane-local online softmax ----
    float pmax = s[0][0];
#pragma unroll
    for (int t = 0; t < 4; ++t)
#pragma unroll
      for (int r = 0; r < 4; ++r) pmax = fmaxf(pmax, s[t][r]);
    pmax = fmaxf(pmax, __shfl_xor(pmax, 16));
    pmax = fmaxf(pmax, __shfl_xor(pmax, 32));

    float cr = 1.0f;
    if (__any(pmax > mrun + 8.0f)) {        // defer-max
      float mnew = fmaxf(mrun, pmax);
      cr = __builtin_amdgcn_exp2f((mrun - mnew) * 1.44269504f);
      lrun *= cr; mrun = mnew;
    }
    if (lane == 0) sCr[wid] = cr;

    const float mk = mrun * 1.44269504f;
    float ps[4][4];
    float psum = 0.f;
#pragma unroll
    for (int t = 0; t < 4; ++t)
#pragma unroll
      for (int r = 0; r < 4; ++r) {
        float p = __builtin_amdgcn_exp2f(s[t][r] * 1.44269504f - mk);
        ps[t][r] = p; psum += p;
      }
    psum += __shfl_xor(psum, 16);
    psum += __shfl_xor(psum, 32);
    lrun += psum;

    // ---- pack P^T -> sP[w] (cvt_pk, swizzled) ----
#pragma unroll
    for (int t = 0; t < 4; ++t) {
      unsigned w0 = cvt_pk_bf16(ps[t][0], ps[t][1]);
      unsigned w1 = cvt_pk_bf16(ps[t][2], ps[t][3]);
      int c = (2 * t + (hi >> 1)) ^ key;
      *(uint2*)(myP + lq * 128 + (c << 4) + ((hi & 1) << 3)) = make_uint2(w0, w1);
    }

    asm volatile("s_waitcnt vmcnt(0) lgkmcnt(0)" ::: "memory");  // V + P ready
    __builtin_amdgcn_sched_barrier(0);
    __builtin_amdgcn_s_barrier();                       // bar2

    // ---- issue K tile kt+1 (latency hides under PV) ----
    if (kt < 23) {
      gload16(pk[0], dk[0]); gload16(pk[1], dk[1]);
      pk[0] += 4096; pk[1] += 4096;
    }

    // ---- rescale (cross-wave factors) ----
    float c0 = sCr[g0], c1 = sCr[g1];
    if (c0 != 1.0f) {
#pragma unroll
      for (int ft = 0; ft < 8; ++ft) {
        acc[0][ft][0] *= c0; acc[0][ft][1] *= c0;
        acc[0][ft][2] *= c0; acc[0][ft][3] *= c0;
      }
    }
    if (c1 != 1.0f) {
#pragma unroll
      for (int ft = 0; ft < 8; ++ft) {
        acc[1][ft][0] *= c1; acc[1][ft][1] *= c1;
        acc[1][ft][2] *= c1; acc[1][ft][3] *= c1;
      }
    }

    // ---- PV on f-half fh for groups g0,g1 ----
    bf16x8 pb00 = *(const bf16x8*)(rP0 + lq * 128 + ((hi ^ key) << 4));
    bf16x8 pb01 = *(const bf16x8*)(rP0 + lq * 128 + (((4 + hi) ^ key) << 4));
    bf16x8 pb10 = *(const bf16x8*)(rP1 + lq * 128 + ((hi ^ key) << 4));
    bf16x8 pb11 = *(const bf16x8*)(rP1 + lq * 128 + (((4 + hi) ^ key) << 4));

    __builtin_amdgcn_s_setprio(1);
#pragma unroll
    for (int ft = 0; ft < 8; ++ft) {
      const unsigned short* vr = &sV[(fh * 128 + ft * 16 + lq) * 64];
      bf16x8 vf0 = *(const bf16x8*)(vr + ((hi ^ key) * 8));
      bf16x8 vf1 = *(const bf16x8*)(vr + (((4 + hi) ^ key) * 8));
      acc[0][ft] = MFMA16(vf0, pb00, acc[0][ft]);
      acc[0][ft] = MFMA16(vf1, pb01, acc[0][ft]);
      acc[1][ft] = MFMA16(vf0, pb10, acc[1][ft]);
      acc[1][ft] = MFMA16(vf1, pb11, acc[1][ft]);
    }
    __builtin_amdgcn_s_setprio(0);

    asm volatile("s_waitcnt lgkmcnt(0)" ::: "memory");
    __builtin_amdgcn_sched_barrier(0);
    __builtin_amdgcn_s_barrier();                       // bar3
  }

  // ---- epilogue: 1/l per group; store bf16 partials + (m,l) ----
  if (hi == 0) {
    sInv[wid][lq] = 1.0f / lrun;
    float* ml = (float*)(wsb + oMl);
    size_t qi = (size_t)(kvh * 8 + bm) * 3072 + q0 + wid * 16 + lq;
    *(float2*)(ml + qi * 2) = make_float2(mrun, lrun);
  }
  __syncthreads();

  unsigned short* paB = (unsigned short*)(wsb + oPa) + (size_t)(kvh * 8 + bm) * 3072 * 256;
#pragma unroll
  for (int gi = 0; gi < 2; ++gi) {
    int g = gp * 2 + gi;
    float inv = sInv[g][lq];
    unsigned short* orow = paB + (size_t)(q0 + g * 16 + lq) * 256 + fh * 128 + hi * 4;
#pragma unroll
    for (int ft = 0; ft < 8; ++ft) {
      u16x4 pk4;
#pragma unroll
      for (int r = 0; r < 4; ++r) pk4[r] = f2bf(acc[gi][ft][r] * inv);
      *(u16x4*)(orow + ft * 16) = pk4;
    }
  }
}

// ================= kernel 4: combine + FFN + LN + mode aggregation ===========
// grid 384 = 2 b x 192 u-blocks of 16. Rows: row = m*16 + du (64 rows).
__global__ __launch_bounds__(256, 2) void ffn_kernel(char* __restrict__ wsb,
                                                     const float* __restrict__ bmid,
                                                     const float* __restrict__ bout,
                                                     const float* __restrict__ lng,
                                                     const float* __restrict__ lnb,
                                                     const float* __restrict__ wagg,
                                                     const float* __restrict__ bagg,
                                                     float* __restrict__ out) {
  __shared__ unsigned short sA[64 * 256];   // 32KB combined fused bf16 (swizzled)
  __shared__ unsigned short sM[64 * 256];   // 32KB mid bf16 (swizzled)
  __shared__ float redS[4][64], redQ[4][64], redC[4][64];
  __shared__ float sSc[64];
  __shared__ float sW0[64], sW1[64];

  const int lane = threadIdx.x & 63, wid = threadIdx.x >> 6;
  const int lq = lane & 15, hi = lane >> 4;
  const int b = blockIdx.x / 192;
  const int u0 = (blockIdx.x % 192) * 16;

  const unsigned short* Wm = (const unsigned short*)(wsb + oWm);
  const unsigned short* Wo = (const unsigned short*)(wsb + oWo);
  const unsigned short* pa = (const unsigned short*)(wsb + oPa);
  const float* mlb = (const float*)(wsb + oMl);

  // ---- combine weights per row ----
  if (threadIdx.x < 64) {
    int m = threadIdx.x >> 4, du = threadIdx.x & 15;
    size_t qi = (size_t)(b * 4 + m) * 3072 + u0 + du;
    float2 ml0 = *(const float2*)(mlb + qi * 2);
    float2 ml1 = *(const float2*)(mlb + (qi + 8ull * 3072) * 2);
    float M = fmaxf(ml0.x, ml1.x);
    float e0 = ml0.y * __builtin_amdgcn_exp2f((ml0.x - M) * 1.44269504f);
    float e1 = ml1.y * __builtin_amdgcn_exp2f((ml1.x - M) * 1.44269504f);
    float inv = 1.0f / (e0 + e1);
    sW0[threadIdx.x] = e0 * inv;
    sW1[threadIdx.x] = e1 * inv;
  }
  __syncthreads();

  // ---- stage combined fused rows -> sA (bf16, swizzled) ----
  {
    int t = threadIdx.x;
#pragma unroll
    for (int j = 0; j < 8; ++j) {
      int i = j * 256 + t;             // chunk index over [64 rows][32 chunks]
      int row = i >> 5, c = i & 31;
      int m = row >> 4, du = row & 15;
      const unsigned short* p0 = pa + ((size_t)(b * 4 + m) * 3072 + u0 + du) * 256 + c * 8;
      bf16x8 a = *(const bf16x8*)(p0);
      bf16x8 bb = *(const bf16x8*)(p0 + 8ull * 3072 * 256);
      float w0 = sW0[row], w1 = sW1[row];
      u16x4 oA, oB;
#pragma unroll
      for (int e = 0; e < 4; ++e) {
        oA[e] = f2bf(w0 * bf2f((unsigned short)a[e]) + w1 * bf2f((unsigned short)bb[e]));
        oB[e] = f2bf(w0 * bf2f((unsigned short)a[e + 4]) + w1 * bf2f((unsigned short)bb[e + 4]));
      }
      unsigned short* dst = &sA[row * 256 + ((c ^ (row & 7)) << 3)];
      *(u16x4*)(dst) = oA;
      *(u16x4*)(dst + 4) = oB;
    }
  }
  __syncthreads();

  const int n0 = wid * 64;
  const int rowb = hi * 4;

  // ---- GEMM1: fused @ Wm^T ----
  f32x4 acc1[4][4];
#pragma unroll
  for (int rg = 0; rg < 4; ++rg)
#pragma unroll
    for (int bt = 0; bt < 4; ++bt) acc1[rg][bt] = (f32x4){0.f, 0.f, 0.f, 0.f};
#pragma unroll
  for (int ks = 0; ks < 8; ++ks) {
    bf16x8 a[4];
#pragma unroll
    for (int rg = 0; rg < 4; ++rg)
      a[rg] = *(const bf16x8*)&sA[(rg * 16 + lq) * 256 + (((ks * 4 + hi) ^ (lq & 7)) << 3)];
#pragma unroll
    for (int bt = 0; bt < 4; ++bt) {
      int n = n0 + bt * 16 + lq;
      bf16x8 bfr = *(const bf16x8*)(Wm + (size_t)n * 256 + ks * 32 + hi * 8);
#pragma unroll
      for (int rg = 0; rg < 4; ++rg) acc1[rg][bt] = MFMA16(a[rg], bfr, acc1[rg][bt]);
    }
  }
  // gelu -> sM
#pragma unroll
  for (int bt = 0; bt < 4; ++bt) {
    int n = n0 + bt * 16 + lq;
    float bb = bmid[n];
#pragma unroll
    for (int rg = 0; rg < 4; ++rg)
#pragma unroll
      for (int r = 0; r < 4; ++r) {
        float x = acc1[rg][bt][r] + bb;
        float g = 0.5f * x * (1.0f + erff(x * 0.7071067811865475f));
        int row = rg * 16 + rowb + r;
        sM[row * 256 + (((n >> 3) ^ (row & 7)) << 3) + (n & 7)] = f2bf(g);
      }
  }
  __syncthreads();

  // ---- GEMM2: mid @ Wo^T ----
  f32x4 acc2[4][4];
#pragma unroll
  for (int rg = 0; rg < 4; ++rg)
#pragma unroll
    for (int bt = 0; bt < 4; ++bt) acc2[rg][bt] = (f32x4){0.f, 0.f, 0.f, 0.f};
#pragma unroll
  for (int ks = 0; ks < 8; ++ks) {
    bf16x8 a[4];
#pragma unroll
    for (int rg = 0; rg < 4; ++rg)
      a[rg] = *(const bf16x8*)&sM[(rg * 16 + lq) * 256 + (((ks * 4 + hi) ^ (lq & 7)) << 3)];
#pragma unroll
    for (int bt = 0; bt < 4; ++bt) {
      int n = n0 + bt * 16 + lq;
      bf16x8 bfr = *(const bf16x8*)(Wo + (size_t)n * 256 + ks * 32 + hi * 8);
#pragma unroll
      for (int rg = 0; rg < 4; ++rg) acc2[rg][bt] = MFMA16(a[rg], bfr, acc2[rg][bt]);
    }
  }

  // ---- + b_out + residual; LN partial sums ----
  float sS[4][4], sQ[4][4];
#pragma unroll
  for (int rg = 0; rg < 4; ++rg)
#pragma unroll
    for (int r = 0; r < 4; ++r) { sS[rg][r] = 0.f; sQ[rg][r] = 0.f; }
#pragma unroll
  for (int bt = 0; bt < 4; ++bt) {
    int n = n0 + bt * 16 + lq;
    float bo = bout[n];
#pragma unroll
    for (int rg = 0; rg < 4; ++rg)
#pragma unroll
      for (int r = 0; r < 4; ++r) {
        int row = rg * 16 + rowb + r;
        float res = bf2f(sA[row * 256 + (((n >> 3) ^ (row & 7)) << 3) + (n & 7)]);
        float x = acc2[rg][bt][r] + bo + res;
        acc2[rg][bt][r] = x;
        sS[rg][r] += x;
        sQ[rg][r] += x * x;
      }
  }
#pragma unroll
  for (int rg = 0; rg < 4; ++rg)
#pragma unroll
    for (int r = 0; r < 4; ++r) {
#pragma unroll
      for (int off = 1; off < 16; off <<= 1) {
        sS[rg][r] += __shfl_xor(sS[rg][r], off);
        sQ[rg][r] += __shfl_xor(sQ[rg][r], off);
      }
    }
  if (lq == 0) {
#pragma unroll
    for (int rg = 0; rg < 4; ++rg)
#pragma unroll
      for (int r = 0; r < 4; ++r) {
        int row = rg * 16 + rowb + r;
        redS[wid][row] = sS[rg][r]; redQ[wid][row] = sQ[rg][r];
      }
  }
  __syncthreads();

  // ---- LN transform (in-place into acc2) + agg score partials ----
  float scp[4][4];
#pragma unroll
  for (int rg = 0; rg < 4; ++rg)
#pragma unroll
    for (int r = 0; r < 4; ++r) {
      int row = rg * 16 + rowb + r;
      float ts = redS[0][row] + redS[1][row] + redS[2][row] + redS[3][row];
      float tq = redQ[0][row] + redQ[1][row] + redQ[2][row] + redQ[3][row];
      float mean = ts * (1.0f / 256.0f);
      float var = tq * (1.0f / 256.0f) - mean * mean;
      float rs = rsqrtf(var + 1e-12f);
      float sc = 0.f;
#pragma unroll
      for (int bt = 0; bt < 4; ++bt) {
        int n = n0 + bt * 16 + lq;
        float o = (acc2[rg][bt][r] - mean) * rs * lng[n] + lnb[n];
        acc2[rg][bt][r] = o;
        sc += o * wagg[n];
      }
      scp[rg][r] = sc;
    }
#pragma unroll
  for (int rg = 0; rg < 4; ++rg)
#pragma unroll
    for (int r = 0; r < 4; ++r) {
#pragma unroll
      for (int off = 1; off < 16; off <<= 1) scp[rg][r] += __shfl_xor(scp[rg][r], off);
    }
  if (lq == 0) {
#pragma unroll
    for (int rg = 0; rg < 4; ++rg)
#pragma unroll
      for (int r = 0; r < 4; ++r) redC[wid][rg * 16 + rowb + r] = scp[rg][r];
  }
  __syncthreads();

  if (threadIdx.x < 64) {
    int t = threadIdx.x;
    sSc[t] = redC[0][t] + redC[1][t] + redC[2][t] + redC[3][t] + bagg[0];
  }
  __syncthreads();

  // ---- mode softmax + weighted sum ----
  float wmode[4][4];   // [r][m]
#pragma unroll
  for (int r = 0; r < 4; ++r) {
    int du = rowb + r;
    float s0 = sSc[du], s1 = sSc[16 + du], s2 = sSc[32 + du], s3 = sSc[48 + du];
    float mx = fmaxf(fmaxf(s0, s1), fmaxf(s2, s3));
    float e0 = __builtin_amdgcn_exp2f((s0 - mx) * 1.44269504f);
    float e1 = __builtin_amdgcn_exp2f((s1 - mx) * 1.44269504f);
    float e2 = __builtin_amdgcn_exp2f((s2 - mx) * 1.44269504f);
    float e3 = __builtin_amdgcn_exp2f((s3 - mx) * 1.44269504f);
    float inv = 1.0f / (e0 + e1 + e2 + e3);
    wmode[r][0] = e0 * inv; wmode[r][1] = e1 * inv;
    wmode[r][2] = e2 * inv; wmode[r][3] = e3 * inv;
  }
#pragma unroll
  for (int bt = 0; bt < 4; ++bt) {
    int n = n0 + bt * 16 + lq;
#pragma unroll
    for (int r = 0; r < 4; ++r) {
      int du = rowb + r;
      float val = wmode[r][0] * acc2[0][bt][r] + wmode[r][1] * acc2[1][bt][r]
                + wmode[r][2] * acc2[2][bt][r] + wmode[r][3] * acc2[3][bt][r];
      out[((size_t)(b * 3072 + u0 + du)) * 256 + n] = val;
    }
  }
}

// ================= launcher =================
extern "C" void kernel_launch(void* const* d_in, const int* in_sizes, int n_in,
                              void* d_out, int out_size, void* d_ws, size_t ws_size,
                              hipStream_t stream) {
  const float* q  = (const float*)d_in[0];
  const float* k  = (const float*)d_in[1];
  const float* wq = (const float*)d_in[2];
  const float* wv = (const float*)d_in[3];
  const float* bv = (const float*)d_in[4];
  const float* wm = (const float*)d_in[5];
  const float* bm = (const float*)d_in[6];
  const float* wo = (const float*)d_in[7];
  const float* bo = (const float*)d_in[8];
  const float* lg = (const float*)d_in[9];
  const float* lb = (const float*)d_in[10];
  const float* wa = (const float*)d_in[11];
  const float* ba = (const float*)d_in[12];
  char* wsb = (char*)d_ws;

  cvt_kernel<<<3520, 256, 0, stream>>>(q, k, wq, wv, wm, wo, (unsigned short*)wsb);
  proj_kernel<<<2304, 256, 0, stream>>>(bv, wsb);
  attn_kernel<<<768, 256, 0, stream>>>(wsb);
  ffn_kernel<<<384, 256, 0, stream>>>(wsb, bm, bo, lg, lb, wa, ba, (float*)d_out);
}